// Round 1
// baseline (14263.893 us; speedup 1.0000x reference)
//
#include <hip/hip_runtime.h>
#include <hip/hip_bf16.h>
#include <math.h>

// ---------------- problem constants ----------------
#define BB 16
#define SS 289          // 1 cls + 288 selected tokens
#define DD 768
#define FFD 3072
#define NHD 12
#define NLAY 12
#define KSEL 288
#define NPATCH 576
#define ATT_LD 292      // padded score-row stride (16B-aligned rows)

__device__ __forceinline__ float gelu_f(float v) {
    return 0.5f * v * (1.0f + erff(v * 0.70710678118654752f));
}

// ---------------- patch pooling (channel 0, 16x16 mean) ----------------
__global__ __launch_bounds__(256) void pool_kernel(const float* __restrict__ x,
                                                   float* __restrict__ pooled) {
    int bp = blockIdx.x;                 // b*576 + p
    int b = bp / NPATCH, p = bp - b * NPATCH;
    int gi = p / 24, gj = p - gi * 24;
    int tid = threadIdx.x;
    int pi = tid >> 4, pj = tid & 15;
    float v = x[((size_t)(b * 3) * 384 + gi * 16 + pi) * 384 + gj * 16 + pj];
    #pragma unroll
    for (int o = 32; o > 0; o >>= 1) v += __shfl_down(v, o);
    __shared__ float red[4];
    if ((tid & 63) == 0) red[tid >> 6] = v;
    __syncthreads();
    if (tid == 0) pooled[bp] = (red[0] + red[1] + red[2] + red[3]) * (1.0f / 256.0f);
}

// ---------------- exact stable top-k via rank counting ----------------
__global__ __launch_bounds__(576) void topk_kernel(const float* __restrict__ pooled,
                                                   int* __restrict__ idxsel) {
    __shared__ float a[NPATCH];
    int b = blockIdx.x, tid = threadIdx.x;
    a[tid] = fabsf(pooled[b * NPATCH + tid]);
    __syncthreads();
    float mine = a[tid];
    int rank = 0;
    for (int j = 0; j < NPATCH; ++j) {
        float aj = a[j];
        rank += (aj > mine) || (aj == mine && j < tid);
    }
    if (rank < KSEL) idxsel[b * KSEL + rank] = tid;
}

// ---------------- patch_w (D, C*P*P) -> transposed (C*P*P, D) ----------------
__global__ __launch_bounds__(256) void transpose_pw(const float* __restrict__ pw,
                                                    float* __restrict__ pwT) {
    int idx = blockIdx.x * 256 + threadIdx.x;    // over 768*768
    int d = idx / 768, k = idx - d * 768;
    pwT[(size_t)k * 768 + d] = pw[idx];
}

// ---------------- im2col of SELECTED patches only ----------------
__global__ __launch_bounds__(256) void im2col_kernel(const float* __restrict__ x,
                                                     const int* __restrict__ idxsel,
                                                     float* __restrict__ col) {
    int t = blockIdx.x;                  // 0 .. B*KSEL-1
    int b = t / KSEL, r = t - b * KSEL;
    int p = idxsel[b * KSEL + r];
    int gi = p / 24, gj = p - gi * 24;
    int tid = threadIdx.x;
    int pi = tid >> 4, pj = tid & 15;
    float* crow = col + (size_t)t * 768;
    #pragma unroll
    for (int c = 0; c < 3; ++c)
        crow[c * 256 + tid] =
            x[((size_t)(b * 3 + c) * 384 + gi * 16 + pi) * 384 + gj * 16 + pj];
}

// ---------------- assemble h: cls + selected tokens + pos_emb ----------------
__global__ __launch_bounds__(256) void assemble_tokens(const float* __restrict__ temp,
                                                       const float* __restrict__ cls_tok,
                                                       const float* __restrict__ pos_emb,
                                                       const int* __restrict__ idxsel,
                                                       float* __restrict__ h) {
    int row = blockIdx.x;                // 0 .. B*SS-1
    int b = row / SS, s = row - b * SS;
    int tid = threadIdx.x;
    float* hrow = h + (size_t)row * DD;
    if (s == 0) {
        #pragma unroll
        for (int c = 0; c < 3; ++c) {
            int j = c * 256 + tid;
            hrow[j] = cls_tok[j] + pos_emb[j];
        }
    } else {
        int r = s - 1;
        int p = idxsel[b * KSEL + r];
        const float* trow = temp + (size_t)(b * KSEL + r) * DD;  // bias already in GEMM
        const float* pe = pos_emb + (size_t)(1 + p) * DD;
        #pragma unroll
        for (int c = 0; c < 3; ++c) {
            int j = c * 256 + tid;
            hrow[j] = trow[j] + pe[j];
        }
    }
}

// ---------------- LayerNorm over 768 (one block per row) ----------------
__global__ __launch_bounds__(256) void ln_kernel(const float* __restrict__ in,
                                                 float* __restrict__ out,
                                                 const float* __restrict__ g,
                                                 const float* __restrict__ be,
                                                 size_t in_stride) {
    int row = blockIdx.x;
    const float* r = in + (size_t)row * in_stride;
    float* w = out + (size_t)row * DD;
    int tid = threadIdx.x;
    float v0 = r[tid], v1 = r[256 + tid], v2 = r[512 + tid];
    float s = v0 + v1 + v2;
    #pragma unroll
    for (int o = 32; o > 0; o >>= 1) s += __shfl_down(s, o);
    __shared__ float red[4];
    if ((tid & 63) == 0) red[tid >> 6] = s;
    __syncthreads();
    float mu = (red[0] + red[1] + red[2] + red[3]) * (1.0f / 768.0f);
    float d0 = v0 - mu, d1 = v1 - mu, d2 = v2 - mu;
    float q = d0 * d0 + d1 * d1 + d2 * d2;
    #pragma unroll
    for (int o = 32; o > 0; o >>= 1) q += __shfl_down(q, o);
    __syncthreads();
    if ((tid & 63) == 0) red[tid >> 6] = q;
    __syncthreads();
    float var = (red[0] + red[1] + red[2] + red[3]) * (1.0f / 768.0f);
    float rs = rsqrtf(var + 1e-6f);
    w[tid]       = d0 * rs * g[tid]       + be[tid];
    w[256 + tid] = d1 * rs * g[256 + tid] + be[256 + tid];
    w[512 + tid] = d2 * rs * g[512 + tid] + be[512 + tid];
}

// ---------------- generic tiled fp32 GEMM: C = A@B (+bias)(gelu)(+res) ----------------
// 64x64 tile, BK=16, 256 threads, 4x4 per thread, float4 LDS paths.
__global__ __launch_bounds__(256) void gemm_f32(const float* __restrict__ A,
                                                const float* __restrict__ Bm,
                                                float* __restrict__ Cm,
                                                const float* __restrict__ bias,
                                                const float* __restrict__ res,
                                                int M, int N, int Kd, int act) {
    __shared__ float As[16][68];   // [k][m], padded: 2-way max on store, f4 on read
    __shared__ float Bs[16][64];   // [k][n]
    int tid = threadIdx.x;
    int m0 = blockIdx.y << 6;
    int n0 = blockIdx.x << 6;
    int tx = tid & 15, ty = tid >> 4;
    int arow = tid >> 2, acol = (tid & 3) << 2;
    int brow = tid >> 4, bcol = (tid & 15) << 2;
    float acc[4][4] = {};
    for (int k0 = 0; k0 < Kd; k0 += 16) {
        float4 av = make_float4(0.f, 0.f, 0.f, 0.f);
        int gm = m0 + arow;
        if (gm < M) av = *(const float4*)&A[(size_t)gm * Kd + k0 + acol];
        As[acol + 0][arow] = av.x;
        As[acol + 1][arow] = av.y;
        As[acol + 2][arow] = av.z;
        As[acol + 3][arow] = av.w;

        float4 bv = make_float4(0.f, 0.f, 0.f, 0.f);
        int gn = n0 + bcol;
        const float* brp = &Bm[(size_t)(k0 + brow) * N];
        if (gn + 3 < N) bv = *(const float4*)&brp[gn];
        else if (gn < N) {
            bv.x = brp[gn];
            if (gn + 1 < N) bv.y = brp[gn + 1];
            if (gn + 2 < N) bv.z = brp[gn + 2];
        }
        *(float4*)&Bs[brow][bcol] = bv;
        __syncthreads();
        #pragma unroll
        for (int kk = 0; kk < 16; ++kk) {
            float a[4], b[4];
            *(float4*)a = *(const float4*)&As[kk][ty << 2];
            *(float4*)b = *(const float4*)&Bs[kk][tx << 2];
            #pragma unroll
            for (int i = 0; i < 4; ++i)
                #pragma unroll
                for (int j = 0; j < 4; ++j)
                    acc[i][j] = fmaf(a[i], b[j], acc[i][j]);
        }
        __syncthreads();
    }
    #pragma unroll
    for (int i = 0; i < 4; ++i) {
        int gm = m0 + (ty << 2) + i;
        if (gm >= M) continue;
        #pragma unroll
        for (int j = 0; j < 4; ++j) {
            int gn = n0 + (tx << 2) + j;
            if (gn >= N) continue;
            float v = acc[i][j];
            if (bias) v += bias[gn];
            if (act) v = gelu_f(v);
            if (res) v += res[(size_t)gm * N + gn];
            Cm[(size_t)gm * N + gn] = v;
        }
    }
}

// ---------------- attention: scores = scale * Q K^T ----------------
__global__ __launch_bounds__(64) void attn_scores(const float* __restrict__ qkv,
                                                  float* __restrict__ att) {
    int bh = blockIdx.z;
    int b = bh / NHD, hd = bh - b * NHD;
    int q0 = blockIdx.y << 5, k0 = blockIdx.x << 5;
    __shared__ float Qs[32][68], Ks[32][68];
    int tid = threadIdx.x;
    const float* qbase = qkv + (size_t)b * SS * 2304 + hd * 64;
    const float* kbase = qbase + 768;
    int rr = tid >> 4, c4 = (tid & 15) << 2;
    #pragma unroll
    for (int it = 0; it < 8; ++it) {
        int r = rr + (it << 2);
        float4 qv = make_float4(0.f, 0.f, 0.f, 0.f), kv = qv;
        if (q0 + r < SS) qv = *(const float4*)&qbase[(size_t)(q0 + r) * 2304 + c4];
        if (k0 + r < SS) kv = *(const float4*)&kbase[(size_t)(k0 + r) * 2304 + c4];
        *(float4*)&Qs[r][c4] = qv;
        *(float4*)&Ks[r][c4] = kv;
    }
    __syncthreads();
    int tx = tid & 7, ty = tid >> 3;
    float acc[4][4] = {};
    for (int d = 0; d < 64; d += 4) {
        float a[4][4], bb[4][4];
        #pragma unroll
        for (int i = 0; i < 4; ++i) *(float4*)a[i] = *(const float4*)&Qs[(ty << 2) + i][d];
        #pragma unroll
        for (int j = 0; j < 4; ++j) *(float4*)bb[j] = *(const float4*)&Ks[(tx << 2) + j][d];
        #pragma unroll
        for (int i = 0; i < 4; ++i)
            #pragma unroll
            for (int j = 0; j < 4; ++j)
                acc[i][j] += a[i][0] * bb[j][0] + a[i][1] * bb[j][1] +
                             a[i][2] * bb[j][2] + a[i][3] * bb[j][3];
    }
    #pragma unroll
    for (int i = 0; i < 4; ++i) {
        int q = q0 + (ty << 2) + i;
        if (q >= SS) continue;
        #pragma unroll
        for (int j = 0; j < 4; ++j) {
            int k = k0 + (tx << 2) + j;
            if (k >= SS) continue;
            att[((size_t)bh * SS + q) * ATT_LD + k] = acc[i][j] * 0.125f;
        }
    }
}

// ---------------- softmax over k (row length 289) ----------------
__global__ __launch_bounds__(64) void softmax_rows(float* __restrict__ att) {
    size_t row = blockIdx.x;
    float* r = att + row * ATT_LD;
    int lane = threadIdx.x;
    float vals[5];
    float m = -1e30f;
    #pragma unroll
    for (int it = 0; it < 5; ++it) {
        int j = lane + (it << 6);
        vals[it] = (j < SS) ? r[j] : -1e30f;
        m = fmaxf(m, vals[it]);
    }
    #pragma unroll
    for (int o = 32; o > 0; o >>= 1) m = fmaxf(m, __shfl_down(m, o));
    m = __shfl(m, 0);
    float s = 0.f;
    #pragma unroll
    for (int it = 0; it < 5; ++it) {
        vals[it] = expf(vals[it] - m);
        if (lane + (it << 6) < SS) s += vals[it];
    }
    #pragma unroll
    for (int o = 32; o > 0; o >>= 1) s += __shfl_down(s, o);
    s = __shfl(s, 0);
    float inv = 1.0f / s;
    #pragma unroll
    for (int it = 0; it < 5; ++it) {
        int j = lane + (it << 6);
        if (j < SS) r[j] = vals[it] * inv;
    }
}

// ---------------- O = P @ V ----------------
__global__ __launch_bounds__(64) void attn_pv(const float* __restrict__ att,
                                              const float* __restrict__ qkv,
                                              float* __restrict__ o) {
    int bh = blockIdx.y;
    int b = bh / NHD, hd = bh - b * NHD;
    int q0 = blockIdx.x << 5;
    __shared__ float Ps[32][36];
    __shared__ float Vs[32][68];
    int tid = threadIdx.x;
    const float* vbase = qkv + (size_t)b * SS * 2304 + 1536 + hd * 64;
    float acc[4][8] = {};
    for (int k0 = 0; k0 < SS; k0 += 32) {
        #pragma unroll
        for (int it = 0; it < 4; ++it) {
            int r = (tid >> 3) + (it << 3);
            int c = (tid & 7) << 2;
            float4 v = make_float4(0.f, 0.f, 0.f, 0.f);
            int q = q0 + r, k = k0 + c;
            if (q < SS) {
                const float* pr = att + ((size_t)bh * SS + q) * ATT_LD;
                if (k + 3 < SS) v = *(const float4*)&pr[k];
                else {
                    if (k < SS) v.x = pr[k];
                    if (k + 1 < SS) v.y = pr[k + 1];
                    if (k + 2 < SS) v.z = pr[k + 2];
                }
            }
            *(float4*)&Ps[r][c] = v;
        }
        #pragma unroll
        for (int it = 0; it < 8; ++it) {
            int r = (tid >> 4) + (it << 2);
            int c = (tid & 15) << 2;
            float4 v = make_float4(0.f, 0.f, 0.f, 0.f);
            if (k0 + r < SS) v = *(const float4*)&vbase[(size_t)(k0 + r) * 2304 + c];
            *(float4*)&Vs[r][c] = v;
        }
        __syncthreads();
        int tx = tid & 7, ty = tid >> 3;
        #pragma unroll 8
        for (int kk = 0; kk < 32; ++kk) {
            float p[4];
            #pragma unroll
            for (int i = 0; i < 4; ++i) p[i] = Ps[(ty << 2) + i][kk];
            float vv[8];
            *(float4*)&vv[0] = *(const float4*)&Vs[kk][tx << 3];
            *(float4*)&vv[4] = *(const float4*)&Vs[kk][(tx << 3) + 4];
            #pragma unroll
            for (int i = 0; i < 4; ++i)
                #pragma unroll
                for (int j = 0; j < 8; ++j)
                    acc[i][j] = fmaf(p[i], vv[j], acc[i][j]);
        }
        __syncthreads();
    }
    int tx = tid & 7, ty = tid >> 3;
    #pragma unroll
    for (int i = 0; i < 4; ++i) {
        int q = q0 + (ty << 2) + i;
        if (q >= SS) continue;
        float* orow = o + ((size_t)(b * SS + q)) * DD + hd * 64 + (tx << 3);
        #pragma unroll
        for (int j = 0; j < 8; ++j) orow[j] = acc[i][j];
    }
}

// ---------------- workspace layout (float offsets) ----------------
static const size_t OFF_POOLED = 0;          //  9216
static const size_t OFF_IDX    = 10240;      //  4608 ints
static const size_t OFF_PWT    = 15360;      //  589824
static const size_t OFF_H      = 606208;     //  3551232  (B*S*D)
static const size_t OFF_Y      = 4157440;    //  3551232
static const size_t OFF_QKV    = 7708672;    //  10653696 (B*S*3D)
static const size_t OFF_BIG    = 18362368;   //  16202496 (att/hidden/col union)
// total 34,564,864 floats = 138.3 MB

extern "C" void kernel_launch(void* const* d_in, const int* in_sizes, int n_in,
                              void* d_out, int out_size, void* d_ws, size_t ws_size,
                              hipStream_t stream) {
    const float* x       = (const float*)d_in[0];
    const float* patch_w = (const float*)d_in[1];
    const float* patch_b = (const float*)d_in[2];
    const float* cls_tok = (const float*)d_in[3];
    const float* pos_emb = (const float*)d_in[4];
    const float* ln1_g   = (const float*)d_in[5];
    const float* ln1_b   = (const float*)d_in[6];
    const float* Wqkv    = (const float*)d_in[7];
    const float* bqkv    = (const float*)d_in[8];
    const float* Wo      = (const float*)d_in[9];
    const float* bo      = (const float*)d_in[10];
    const float* ln2_g   = (const float*)d_in[11];
    const float* ln2_b   = (const float*)d_in[12];
    const float* W1      = (const float*)d_in[13];
    const float* b1      = (const float*)d_in[14];
    const float* W2      = (const float*)d_in[15];
    const float* b2      = (const float*)d_in[16];
    const float* lnf_g   = (const float*)d_in[17];
    const float* lnf_b   = (const float*)d_in[18];
    const float* fc_w    = (const float*)d_in[19];
    const float* fc_b    = (const float*)d_in[20];
    float* out = (float*)d_out;
    float* ws  = (float*)d_ws;

    float* pooled = ws + OFF_POOLED;
    int*   idxsel = (int*)(ws + OFF_IDX);
    float* pwT    = ws + OFF_PWT;
    float* h      = ws + OFF_H;
    float* y      = ws + OFF_Y;
    float* qkv    = ws + OFF_QKV;
    float* big    = ws + OFF_BIG;   // col -> att scores -> mlp hidden
    float* col    = big;

    auto gemm = [&](const float* A, const float* Bm, float* Cc, const float* bias,
                    const float* res, int M, int N, int Kd, int act) {
        dim3 grid((N + 63) / 64, (M + 63) / 64);
        gemm_f32<<<grid, 256, 0, stream>>>(A, Bm, Cc, bias, res, M, N, Kd, act);
    };

    // ---- sparse selection + patch embedding (selected patches only) ----
    pool_kernel<<<BB * NPATCH, 256, 0, stream>>>(x, pooled);
    topk_kernel<<<BB, 576, 0, stream>>>(pooled, idxsel);
    transpose_pw<<<(768 * 768) / 256, 256, 0, stream>>>(patch_w, pwT);
    im2col_kernel<<<BB * KSEL, 256, 0, stream>>>(x, idxsel, col);
    gemm(col, pwT, y, patch_b, nullptr, BB * KSEL, DD, DD, 0);   // temp tokens -> y
    assemble_tokens<<<BB * SS, 256, 0, stream>>>(y, cls_tok, pos_emb, idxsel, h);

    // ---- transformer layers ----
    for (int i = 0; i < NLAY; ++i) {
        ln_kernel<<<BB * SS, 256, 0, stream>>>(h, y, ln1_g + i * DD, ln1_b + i * DD, DD);
        gemm(y, Wqkv + (size_t)i * DD * 3 * DD, qkv, bqkv + (size_t)i * 3 * DD,
             nullptr, BB * SS, 3 * DD, DD, 0);
        dim3 sg(10, 10, BB * NHD);
        attn_scores<<<sg, 64, 0, stream>>>(qkv, big);
        softmax_rows<<<BB * NHD * SS, 64, 0, stream>>>(big);
        attn_pv<<<dim3(10, BB * NHD), 64, 0, stream>>>(big, qkv, y);
        gemm(y, Wo + (size_t)i * DD * DD, h, bo + (size_t)i * DD, h, BB * SS, DD, DD, 0);
        ln_kernel<<<BB * SS, 256, 0, stream>>>(h, y, ln2_g + i * DD, ln2_b + i * DD, DD);
        gemm(y, W1 + (size_t)i * DD * FFD, big, b1 + (size_t)i * FFD,
             nullptr, BB * SS, FFD, DD, 1);                       // gelu
        gemm(big, W2 + (size_t)i * FFD * DD, h, b2 + (size_t)i * DD, h, BB * SS, DD, FFD, 0);
    }

    // ---- final LN on cls token + classifier ----
    ln_kernel<<<BB, 256, 0, stream>>>(h, y, lnf_g, lnf_b, (size_t)SS * DD);
    gemm(y, fc_w, out, fc_b, nullptr, BB, 1000, DD, 0);
}

// Round 2
// 5131.923 us; speedup vs baseline: 2.7794x; 2.7794x over previous
//
#include <hip/hip_runtime.h>
#include <hip/hip_bf16.h>
#include <math.h>

// ---------------- problem constants ----------------
#define BB 16
#define SS 289          // 1 cls + 288 selected tokens
#define DD 768
#define FFD 3072
#define NHD 12
#define NLAY 12
#define KSEL 288
#define NPATCH 576
#define ATT_LD 292      // padded score-row stride (16B-aligned rows)

typedef short bf16x8 __attribute__((ext_vector_type(8)));
typedef float f32x4 __attribute__((ext_vector_type(4)));

typedef __attribute__((address_space(3))) void lds_t;
typedef __attribute__((address_space(1))) const void glb_t;

__device__ __forceinline__ void gload16(const void* g, void* l) {
    __builtin_amdgcn_global_load_lds((glb_t*)g, (lds_t*)l, 16, 0, 0);
}

__device__ __forceinline__ float gelu_f(float v) {
    return 0.5f * v * (1.0f + erff(v * 0.70710678118654752f));
}

__device__ __forceinline__ void store_val(float* p, float v) { *p = v; }
__device__ __forceinline__ void store_val(__hip_bfloat16* p, float v) { *p = __float2bfloat16(v); }

// ---------------- patch pooling (channel 0, 16x16 mean) ----------------
__global__ __launch_bounds__(256) void pool_kernel(const float* __restrict__ x,
                                                   float* __restrict__ pooled) {
    int bp = blockIdx.x;
    int b = bp / NPATCH, p = bp - b * NPATCH;
    int gi = p / 24, gj = p - gi * 24;
    int tid = threadIdx.x;
    int pi = tid >> 4, pj = tid & 15;
    float v = x[((size_t)(b * 3) * 384 + gi * 16 + pi) * 384 + gj * 16 + pj];
    #pragma unroll
    for (int o = 32; o > 0; o >>= 1) v += __shfl_down(v, o);
    __shared__ float red[4];
    if ((tid & 63) == 0) red[tid >> 6] = v;
    __syncthreads();
    if (tid == 0) pooled[bp] = (red[0] + red[1] + red[2] + red[3]) * (1.0f / 256.0f);
}

// ---------------- exact stable top-k via rank counting ----------------
__global__ __launch_bounds__(576) void topk_kernel(const float* __restrict__ pooled,
                                                   int* __restrict__ idxsel) {
    __shared__ float a[NPATCH];
    int b = blockIdx.x, tid = threadIdx.x;
    a[tid] = fabsf(pooled[b * NPATCH + tid]);
    __syncthreads();
    float mine = a[tid];
    int rank = 0;
    for (int j = 0; j < NPATCH; ++j) {
        float aj = a[j];
        rank += (aj > mine) || (aj == mine && j < tid);
    }
    if (rank < KSEL) idxsel[b * KSEL + rank] = tid;
}

// ---------------- fp32 -> bf16 straight convert ----------------
__global__ __launch_bounds__(256) void convert_bf16(const float* __restrict__ in,
                                                    __hip_bfloat16* __restrict__ out,
                                                    int n) {
    int i = blockIdx.x * 256 + threadIdx.x;
    if (i < n) out[i] = __float2bfloat16(in[i]);
}

// ---------------- W[K][N] fp32 -> WT[N][K] bf16 (tiled transpose) ----------------
__global__ __launch_bounds__(256) void convert_transpose(const float* __restrict__ W,
                                                         __hip_bfloat16* __restrict__ WT,
                                                         int K, int N) {
    __shared__ float tile[32][33];
    int n0 = blockIdx.x * 32, k0 = blockIdx.y * 32;
    int t = threadIdx.x;
    int r = t >> 3, c = (t & 7) << 2;
    float4 v = *(const float4*)&W[(size_t)(k0 + r) * N + n0 + c];
    tile[r][c] = v.x; tile[r][c + 1] = v.y; tile[r][c + 2] = v.z; tile[r][c + 3] = v.w;
    __syncthreads();
    int n = t >> 3, k = (t & 7) << 2;
    __hip_bfloat16* dst = &WT[(size_t)(n0 + n) * K + k0 + k];
    #pragma unroll
    for (int j = 0; j < 4; ++j) dst[j] = __float2bfloat16(tile[k + j][n]);
}

// ---------------- im2col of SELECTED patches only (bf16 out) ----------------
__global__ __launch_bounds__(256) void im2col_kernel(const float* __restrict__ x,
                                                     const int* __restrict__ idxsel,
                                                     __hip_bfloat16* __restrict__ col) {
    int t = blockIdx.x;
    int b = t / KSEL, r = t - b * KSEL;
    int p = idxsel[b * KSEL + r];
    int gi = p / 24, gj = p - gi * 24;
    int tid = threadIdx.x;
    int pi = tid >> 4, pj = tid & 15;
    __hip_bfloat16* crow = col + (size_t)t * 768;
    #pragma unroll
    for (int c = 0; c < 3; ++c)
        crow[c * 256 + tid] = __float2bfloat16(
            x[((size_t)(b * 3 + c) * 384 + gi * 16 + pi) * 384 + gj * 16 + pj]);
}

// ---------------- assemble h: cls + selected tokens + pos_emb (fp32) ----------------
__global__ __launch_bounds__(256) void assemble_tokens(const float* __restrict__ temp,
                                                       const float* __restrict__ cls_tok,
                                                       const float* __restrict__ pos_emb,
                                                       const int* __restrict__ idxsel,
                                                       float* __restrict__ h) {
    int row = blockIdx.x;
    int b = row / SS, s = row - b * SS;
    int tid = threadIdx.x;
    float* hrow = h + (size_t)row * DD;
    if (s == 0) {
        #pragma unroll
        for (int c = 0; c < 3; ++c) {
            int j = c * 256 + tid;
            hrow[j] = cls_tok[j] + pos_emb[j];
        }
    } else {
        int r = s - 1;
        int p = idxsel[b * KSEL + r];
        const float* trow = temp + (size_t)(b * KSEL + r) * DD;
        const float* pe = pos_emb + (size_t)(1 + p) * DD;
        #pragma unroll
        for (int c = 0; c < 3; ++c) {
            int j = c * 256 + tid;
            hrow[j] = trow[j] + pe[j];
        }
    }
}

// ---------------- LayerNorm over 768, templated output dtype ----------------
template <typename T>
__global__ __launch_bounds__(256) void ln_kernel(const float* __restrict__ in,
                                                 T* __restrict__ out,
                                                 const float* __restrict__ g,
                                                 const float* __restrict__ be,
                                                 size_t in_stride) {
    int row = blockIdx.x;
    const float* r = in + (size_t)row * in_stride;
    T* w = out + (size_t)row * DD;
    int tid = threadIdx.x;
    float v0 = r[tid], v1 = r[256 + tid], v2 = r[512 + tid];
    float s = v0 + v1 + v2;
    #pragma unroll
    for (int o = 32; o > 0; o >>= 1) s += __shfl_down(s, o);
    __shared__ float red[4];
    if ((tid & 63) == 0) red[tid >> 6] = s;
    __syncthreads();
    float mu = (red[0] + red[1] + red[2] + red[3]) * (1.0f / 768.0f);
    float d0 = v0 - mu, d1 = v1 - mu, d2 = v2 - mu;
    float q = d0 * d0 + d1 * d1 + d2 * d2;
    #pragma unroll
    for (int o = 32; o > 0; o >>= 1) q += __shfl_down(q, o);
    __syncthreads();
    if ((tid & 63) == 0) red[tid >> 6] = q;
    __syncthreads();
    float var = (red[0] + red[1] + red[2] + red[3]) * (1.0f / 768.0f);
    float rs = rsqrtf(var + 1e-6f);
    store_val(&w[tid],       d0 * rs * g[tid]       + be[tid]);
    store_val(&w[256 + tid], d1 * rs * g[256 + tid] + be[256 + tid]);
    store_val(&w[512 + tid], d2 * rs * g[512 + tid] + be[512 + tid]);
}

// ---------------- bf16 MFMA GEMM: C = A[M][K] @ BT[N][K]^T ----------------
// m97 structure: 128x128 tile, BK=32, 4 waves, global_load_lds w=16,
// XOR swizzle kc ^= (m>>1)&3 on 64B rows (staging source + ds_read, both sides).
template <typename OUT_T, int ACT, int RES>
__global__ __launch_bounds__(256) void gemm_bf16(const __hip_bfloat16* __restrict__ A,
                                                 const __hip_bfloat16* __restrict__ BT,
                                                 OUT_T* __restrict__ C,
                                                 const float* __restrict__ bias,
                                                 const float* __restrict__ res,
                                                 int M, int N, int K) {
    __shared__ __hip_bfloat16 smA[128 * 32];
    __shared__ __hip_bfloat16 smB[128 * 32];
    const int t = threadIdx.x;
    const int lane = t & 63, wid = t >> 6;
    const int wr = wid >> 1, wc = wid & 1;        // 2x2 waves, 64x64 each
    const int m0 = blockIdx.y << 7, n0 = blockIdx.x << 7;
    const int l15 = lane & 15, l4 = lane >> 4;

    // fragment read byte offsets (swizzled)
    int ra[4], rb[4];
    #pragma unroll
    for (int f = 0; f < 4; ++f) {
        int ml = wr * 64 + f * 16 + l15;
        ra[f] = ml * 64 + ((l4 ^ ((ml >> 1) & 3)) << 4);
        int nl = wc * 64 + f * 16 + l15;
        rb[f] = nl * 64 + ((l4 ^ ((nl >> 1) & 3)) << 4);
    }

    // staging source element offsets (inverse swizzle), 2 slots/thread each
    size_t aoff[2], boff[2];
    #pragma unroll
    for (int it = 0; it < 2; ++it) {
        int s = it * 256 + t;
        int m = s >> 2;
        int kc = (s & 3) ^ ((m >> 1) & 3);
        int gm = m0 + m; if (gm > M - 1) gm = M - 1;
        aoff[it] = (size_t)gm * K + kc * 8;
        boff[it] = (size_t)(n0 + m) * K + kc * 8;
    }
    char* smAb = (char*)smA;
    char* smBb = (char*)smB;
    const int wb = wid << 10;                      // wave-uniform LDS base

    f32x4 acc[4][4];
    #pragma unroll
    for (int i = 0; i < 4; ++i)
        #pragma unroll
        for (int j = 0; j < 4; ++j) acc[i][j] = (f32x4){0.f, 0.f, 0.f, 0.f};

    for (int k0 = 0; k0 < K; k0 += 32) {
        gload16(A + aoff[0] + k0, smAb + wb);
        gload16(A + aoff[1] + k0, smAb + 4096 + wb);
        gload16(BT + boff[0] + k0, smBb + wb);
        gload16(BT + boff[1] + k0, smBb + 4096 + wb);
        __syncthreads();
        bf16x8 af[4], bf[4];
        #pragma unroll
        for (int f = 0; f < 4; ++f) {
            af[f] = *(const bf16x8*)(smAb + ra[f]);
            bf[f] = *(const bf16x8*)(smBb + rb[f]);
        }
        #pragma unroll
        for (int i = 0; i < 4; ++i)
            #pragma unroll
            for (int j = 0; j < 4; ++j)
                acc[i][j] = __builtin_amdgcn_mfma_f32_16x16x32_bf16(af[i], bf[j], acc[i][j], 0, 0, 0);
        __syncthreads();
    }

    // epilogue: bias / gelu / residual, fp32 math, templated store
    #pragma unroll
    for (int i = 0; i < 4; ++i) {
        int gmb = m0 + wr * 64 + i * 16 + l4 * 4;
        #pragma unroll
        for (int j = 0; j < 4; ++j) {
            int gn = n0 + wc * 64 + j * 16 + l15;
            float bv = bias ? bias[gn] : 0.f;
            #pragma unroll
            for (int r = 0; r < 4; ++r) {
                int gm = gmb + r;
                if (gm < M) {
                    float v = acc[i][j][r] + bv;
                    if (ACT) v = gelu_f(v);
                    if (RES) v += res[(size_t)gm * N + gn];
                    store_val(&C[(size_t)gm * N + gn], v);
                }
            }
        }
    }
}

// ---------------- fp32 GEMM (head only: 16x1000x768) ----------------
__global__ __launch_bounds__(256) void gemm_f32(const float* __restrict__ A,
                                                const float* __restrict__ Bm,
                                                float* __restrict__ Cm,
                                                const float* __restrict__ bias,
                                                int M, int N, int Kd) {
    __shared__ float As[16][68];
    __shared__ float Bs[16][64];
    int tid = threadIdx.x;
    int m0 = blockIdx.y << 6;
    int n0 = blockIdx.x << 6;
    int tx = tid & 15, ty = tid >> 4;
    int arow = tid >> 2, acol = (tid & 3) << 2;
    int brow = tid >> 4, bcol = (tid & 15) << 2;
    float acc[4][4] = {};
    for (int k0 = 0; k0 < Kd; k0 += 16) {
        float4 av = make_float4(0.f, 0.f, 0.f, 0.f);
        int gm = m0 + arow;
        if (gm < M) av = *(const float4*)&A[(size_t)gm * Kd + k0 + acol];
        As[acol + 0][arow] = av.x;
        As[acol + 1][arow] = av.y;
        As[acol + 2][arow] = av.z;
        As[acol + 3][arow] = av.w;
        float4 bv = make_float4(0.f, 0.f, 0.f, 0.f);
        int gn = n0 + bcol;
        const float* brp = &Bm[(size_t)(k0 + brow) * N];
        if (gn + 3 < N) bv = *(const float4*)&brp[gn];
        else if (gn < N) {
            bv.x = brp[gn];
            if (gn + 1 < N) bv.y = brp[gn + 1];
            if (gn + 2 < N) bv.z = brp[gn + 2];
        }
        *(float4*)&Bs[brow][bcol] = bv;
        __syncthreads();
        #pragma unroll
        for (int kk = 0; kk < 16; ++kk) {
            float a[4], b[4];
            *(float4*)a = *(const float4*)&As[kk][ty << 2];
            *(float4*)b = *(const float4*)&Bs[kk][tx << 2];
            #pragma unroll
            for (int i = 0; i < 4; ++i)
                #pragma unroll
                for (int j = 0; j < 4; ++j)
                    acc[i][j] = fmaf(a[i], b[j], acc[i][j]);
        }
        __syncthreads();
    }
    #pragma unroll
    for (int i = 0; i < 4; ++i) {
        int gm = m0 + (ty << 2) + i;
        if (gm >= M) continue;
        #pragma unroll
        for (int j = 0; j < 4; ++j) {
            int gn = n0 + (tx << 2) + j;
            if (gn >= N) continue;
            Cm[(size_t)gm * N + gn] = acc[i][j] + (bias ? bias[gn] : 0.f);
        }
    }
}

// ---------------- attention (fp32): scores = scale * Q K^T ----------------
__global__ __launch_bounds__(64) void attn_scores(const float* __restrict__ qkv,
                                                  float* __restrict__ att) {
    int bh = blockIdx.z;
    int b = bh / NHD, hd = bh - b * NHD;
    int q0 = blockIdx.y << 5, k0 = blockIdx.x << 5;
    __shared__ float Qs[32][68], Ks[32][68];
    int tid = threadIdx.x;
    const float* qbase = qkv + (size_t)b * SS * 2304 + hd * 64;
    const float* kbase = qbase + 768;
    int rr = tid >> 4, c4 = (tid & 15) << 2;
    #pragma unroll
    for (int it = 0; it < 8; ++it) {
        int r = rr + (it << 2);
        float4 qv = make_float4(0.f, 0.f, 0.f, 0.f), kv = qv;
        if (q0 + r < SS) qv = *(const float4*)&qbase[(size_t)(q0 + r) * 2304 + c4];
        if (k0 + r < SS) kv = *(const float4*)&kbase[(size_t)(k0 + r) * 2304 + c4];
        *(float4*)&Qs[r][c4] = qv;
        *(float4*)&Ks[r][c4] = kv;
    }
    __syncthreads();
    int tx = tid & 7, ty = tid >> 3;
    float acc[4][4] = {};
    for (int d = 0; d < 64; d += 4) {
        float a[4][4], bb[4][4];
        #pragma unroll
        for (int i = 0; i < 4; ++i) *(float4*)a[i] = *(const float4*)&Qs[(ty << 2) + i][d];
        #pragma unroll
        for (int j = 0; j < 4; ++j) *(float4*)bb[j] = *(const float4*)&Ks[(tx << 2) + j][d];
        #pragma unroll
        for (int i = 0; i < 4; ++i)
            #pragma unroll
            for (int j = 0; j < 4; ++j)
                acc[i][j] += a[i][0] * bb[j][0] + a[i][1] * bb[j][1] +
                             a[i][2] * bb[j][2] + a[i][3] * bb[j][3];
    }
    #pragma unroll
    for (int i = 0; i < 4; ++i) {
        int q = q0 + (ty << 2) + i;
        if (q >= SS) continue;
        #pragma unroll
        for (int j = 0; j < 4; ++j) {
            int k = k0 + (tx << 2) + j;
            if (k >= SS) continue;
            att[((size_t)bh * SS + q) * ATT_LD + k] = acc[i][j] * 0.125f;
        }
    }
}

// ---------------- softmax over k (row length 289) ----------------
__global__ __launch_bounds__(64) void softmax_rows(float* __restrict__ att) {
    size_t row = blockIdx.x;
    float* r = att + row * ATT_LD;
    int lane = threadIdx.x;
    float vals[5];
    float m = -1e30f;
    #pragma unroll
    for (int it = 0; it < 5; ++it) {
        int j = lane + (it << 6);
        vals[it] = (j < SS) ? r[j] : -1e30f;
        m = fmaxf(m, vals[it]);
    }
    #pragma unroll
    for (int o = 32; o > 0; o >>= 1) m = fmaxf(m, __shfl_down(m, o));
    m = __shfl(m, 0);
    float s = 0.f;
    #pragma unroll
    for (int it = 0; it < 5; ++it) {
        vals[it] = expf(vals[it] - m);
        if (lane + (it << 6) < SS) s += vals[it];
    }
    #pragma unroll
    for (int o = 32; o > 0; o >>= 1) s += __shfl_down(s, o);
    s = __shfl(s, 0);
    float inv = 1.0f / s;
    #pragma unroll
    for (int it = 0; it < 5; ++it) {
        int j = lane + (it << 6);
        if (j < SS) r[j] = vals[it] * inv;
    }
}

// ---------------- O = P @ V  (fp32 in, bf16 out) ----------------
__global__ __launch_bounds__(64) void attn_pv(const float* __restrict__ att,
                                              const float* __restrict__ qkv,
                                              __hip_bfloat16* __restrict__ o) {
    int bh = blockIdx.y;
    int b = bh / NHD, hd = bh - b * NHD;
    int q0 = blockIdx.x << 5;
    __shared__ float Ps[32][36];
    __shared__ float Vs[32][68];
    int tid = threadIdx.x;
    const float* vbase = qkv + (size_t)b * SS * 2304 + 1536 + hd * 64;
    float acc[4][8] = {};
    for (int k0 = 0; k0 < SS; k0 += 32) {
        #pragma unroll
        for (int it = 0; it < 4; ++it) {
            int r = (tid >> 3) + (it << 3);
            int c = (tid & 7) << 2;
            float4 v = make_float4(0.f, 0.f, 0.f, 0.f);
            int q = q0 + r, k = k0 + c;
            if (q < SS) {
                const float* pr = att + ((size_t)bh * SS + q) * ATT_LD;
                if (k + 3 < SS) v = *(const float4*)&pr[k];
                else {
                    if (k < SS) v.x = pr[k];
                    if (k + 1 < SS) v.y = pr[k + 1];
                    if (k + 2 < SS) v.z = pr[k + 2];
                }
            }
            *(float4*)&Ps[r][c] = v;
        }
        #pragma unroll
        for (int it = 0; it < 8; ++it) {
            int r = (tid >> 4) + (it << 2);
            int c = (tid & 15) << 2;
            float4 v = make_float4(0.f, 0.f, 0.f, 0.f);
            if (k0 + r < SS) v = *(const float4*)&vbase[(size_t)(k0 + r) * 2304 + c];
            *(float4*)&Vs[r][c] = v;
        }
        __syncthreads();
        int tx = tid & 7, ty = tid >> 3;
        #pragma unroll 8
        for (int kk = 0; kk < 32; ++kk) {
            float p[4];
            #pragma unroll
            for (int i = 0; i < 4; ++i) p[i] = Ps[(ty << 2) + i][kk];
            float vv[8];
            *(float4*)&vv[0] = *(const float4*)&Vs[kk][tx << 3];
            *(float4*)&vv[4] = *(const float4*)&Vs[kk][(tx << 3) + 4];
            #pragma unroll
            for (int i = 0; i < 4; ++i)
                #pragma unroll
                for (int j = 0; j < 8; ++j)
                    acc[i][j] = fmaf(p[i], vv[j], acc[i][j]);
        }
        __syncthreads();
    }
    int tx = tid & 7, ty = tid >> 3;
    #pragma unroll
    for (int i = 0; i < 4; ++i) {
        int q = q0 + (ty << 2) + i;
        if (q >= SS) continue;
        __hip_bfloat16* orow = o + ((size_t)(b * SS + q)) * DD + hd * 64 + (tx << 3);
        #pragma unroll
        for (int j = 0; j < 8; ++j) orow[j] = __float2bfloat16(acc[i][j]);
    }
}

// ---------------- workspace layout (float offsets) ----------------
static const size_t OFF_POOLED = 0;           //  9216 f
static const size_t OFF_IDX    = 10240;       //  4608 int
static const size_t OFF_H      = 16384;       //  3,551,232 f
static const size_t OFF_YB     = 3567616;     //  3,551,232 bf16
static const size_t OFF_OB     = 5343232;     //  3,551,232 bf16
static const size_t OFF_QKV    = 7118848;     // 10,653,696 f
static const size_t OFF_WBUF   = 17772544;    //  7,077,888 bf16
static const size_t OFF_PWB    = 21311488;    //    589,824 bf16
static const size_t OFF_YF     = 21606400;    //     12,288 f
static const size_t OFF_BIG    = 21618688;    // 16,201,536 f (att / hidden / col+temp)
// total 37,820,224 floats = 151.3 MB

extern "C" void kernel_launch(void* const* d_in, const int* in_sizes, int n_in,
                              void* d_out, int out_size, void* d_ws, size_t ws_size,
                              hipStream_t stream) {
    const float* x       = (const float*)d_in[0];
    const float* patch_w = (const float*)d_in[1];
    const float* patch_b = (const float*)d_in[2];
    const float* cls_tok = (const float*)d_in[3];
    const float* pos_emb = (const float*)d_in[4];
    const float* ln1_g   = (const float*)d_in[5];
    const float* ln1_b   = (const float*)d_in[6];
    const float* Wqkv    = (const float*)d_in[7];
    const float* bqkv    = (const float*)d_in[8];
    const float* Wo      = (const float*)d_in[9];
    const float* bo      = (const float*)d_in[10];
    const float* ln2_g   = (const float*)d_in[11];
    const float* ln2_b   = (const float*)d_in[12];
    const float* W1      = (const float*)d_in[13];
    const float* b1      = (const float*)d_in[14];
    const float* W2      = (const float*)d_in[15];
    const float* b2      = (const float*)d_in[16];
    const float* lnf_g   = (const float*)d_in[17];
    const float* lnf_b   = (const float*)d_in[18];
    const float* fc_w    = (const float*)d_in[19];
    const float* fc_b    = (const float*)d_in[20];
    float* out = (float*)d_out;
    float* ws  = (float*)d_ws;

    float*          pooled = ws + OFF_POOLED;
    int*            idxsel = (int*)(ws + OFF_IDX);
    float*          h      = ws + OFF_H;
    __hip_bfloat16* yb     = (__hip_bfloat16*)(ws + OFF_YB);
    __hip_bfloat16* ob     = (__hip_bfloat16*)(ws + OFF_OB);
    float*          qkv    = ws + OFF_QKV;
    __hip_bfloat16* wbuf   = (__hip_bfloat16*)(ws + OFF_WBUF);
    __hip_bfloat16* pwb    = (__hip_bfloat16*)(ws + OFF_PWB);
    float*          yf     = ws + OFF_YF;
    float*          big    = ws + OFF_BIG;
    __hip_bfloat16* col    = (__hip_bfloat16*)big;             // 3,538,944 bf16
    float*          temp   = big + 1769472;                    // 3,538,944 f
    __hip_bfloat16* hidden = (__hip_bfloat16*)big;             // 14,204,928 bf16
    float*          att    = big;                              // full region

    // wbuf slices (bf16 element offsets)
    __hip_bfloat16* wqkvT = wbuf;                              // [2304][768]
    __hip_bfloat16* woT   = wbuf + 1769472;                    // [768][768]
    __hip_bfloat16* w1T   = wbuf + 2359296;                    // [3072][768]
    __hip_bfloat16* w2T   = wbuf + 4718592;                    // [768][3072]

    // ---- sparse selection + patch embedding ----
    pool_kernel<<<BB * NPATCH, 256, 0, stream>>>(x, pooled);
    topk_kernel<<<BB, 576, 0, stream>>>(pooled, idxsel);
    convert_bf16<<<(589824 + 255) / 256, 256, 0, stream>>>(patch_w, pwb, 589824);
    im2col_kernel<<<BB * KSEL, 256, 0, stream>>>(x, idxsel, col);
    gemm_bf16<float, 0, 0><<<dim3(6, 36), 256, 0, stream>>>(col, pwb, temp, patch_b,
                                                            nullptr, 4608, DD, DD);
    assemble_tokens<<<BB * SS, 256, 0, stream>>>(temp, cls_tok, pos_emb, idxsel, h);

    const int M = BB * SS;            // 4624
    const int MG = 37;                // ceil(4624/128)

    // ---- transformer layers ----
    for (int i = 0; i < NLAY; ++i) {
        // per-layer weight convert+transpose into rotating bf16 buffer
        convert_transpose<<<dim3(72, 24), 256, 0, stream>>>(Wqkv + (size_t)i * DD * 3 * DD, wqkvT, DD, 3 * DD);
        convert_transpose<<<dim3(24, 24), 256, 0, stream>>>(Wo + (size_t)i * DD * DD, woT, DD, DD);
        convert_transpose<<<dim3(96, 24), 256, 0, stream>>>(W1 + (size_t)i * DD * FFD, w1T, DD, FFD);
        convert_transpose<<<dim3(24, 96), 256, 0, stream>>>(W2 + (size_t)i * FFD * DD, w2T, FFD, DD);

        ln_kernel<__hip_bfloat16><<<M, 256, 0, stream>>>(h, yb, ln1_g + i * DD, ln1_b + i * DD, DD);
        gemm_bf16<float, 0, 0><<<dim3(18, MG), 256, 0, stream>>>(yb, wqkvT, qkv,
                                                                 bqkv + (size_t)i * 3 * DD,
                                                                 nullptr, M, 3 * DD, DD);
        dim3 sg(10, 10, BB * NHD);
        attn_scores<<<sg, 64, 0, stream>>>(qkv, att);
        softmax_rows<<<BB * NHD * SS, 64, 0, stream>>>(att);
        attn_pv<<<dim3(10, BB * NHD), 64, 0, stream>>>(att, qkv, ob);
        gemm_bf16<float, 0, 1><<<dim3(6, MG), 256, 0, stream>>>(ob, woT, h, bo + (size_t)i * DD,
                                                                h, M, DD, DD);
        ln_kernel<__hip_bfloat16><<<M, 256, 0, stream>>>(h, yb, ln2_g + i * DD, ln2_b + i * DD, DD);
        gemm_bf16<__hip_bfloat16, 1, 0><<<dim3(24, MG), 256, 0, stream>>>(yb, w1T, hidden,
                                                                          b1 + (size_t)i * FFD,
                                                                          nullptr, M, FFD, DD);
        gemm_bf16<float, 0, 1><<<dim3(6, MG), 256, 0, stream>>>(hidden, w2T, h,
                                                                b2 + (size_t)i * DD, h, M, DD, FFD);
    }

    // ---- final LN on cls token + fp32 classifier head ----
    ln_kernel<float><<<BB, 256, 0, stream>>>(h, yf, lnf_g, lnf_b, (size_t)SS * DD);
    gemm_f32<<<dim3(16, 1), 256, 0, stream>>>(yf, fc_w, out, fc_b, BB, 1000, DD);
}

// Round 3
// 3415.950 us; speedup vs baseline: 4.1757x; 1.5023x over previous
//
#include <hip/hip_runtime.h>
#include <hip/hip_bf16.h>
#include <math.h>

// ---------------- problem constants ----------------
#define BB 16
#define SS 289          // 1 cls + 288 selected tokens
#define DD 768
#define FFD 3072
#define NHD 12
#define NLAY 12
#define KSEL 288
#define NPATCH 576

typedef short bf16x8 __attribute__((ext_vector_type(8)));
typedef short bf16x4 __attribute__((ext_vector_type(4)));
typedef float f32x4 __attribute__((ext_vector_type(4)));

typedef __attribute__((address_space(3))) void lds_t;
typedef __attribute__((address_space(1))) const void glb_t;

__device__ __forceinline__ void gload16(const void* g, void* l) {
    __builtin_amdgcn_global_load_lds((glb_t*)g, (lds_t*)l, 16, 0, 0);
}

__device__ __forceinline__ float gelu_f(float v) {
    return 0.5f * v * (1.0f + erff(v * 0.70710678118654752f));
}

__device__ __forceinline__ void store_val(float* p, float v) { *p = v; }
__device__ __forceinline__ void store_val(__hip_bfloat16* p, float v) { *p = __float2bfloat16(v); }

// ---------------- patch pooling (channel 0, 16x16 mean) ----------------
__global__ __launch_bounds__(256) void pool_kernel(const float* __restrict__ x,
                                                   float* __restrict__ pooled) {
    int bp = blockIdx.x;
    int b = bp / NPATCH, p = bp - b * NPATCH;
    int gi = p / 24, gj = p - gi * 24;
    int tid = threadIdx.x;
    int pi = tid >> 4, pj = tid & 15;
    float v = x[((size_t)(b * 3) * 384 + gi * 16 + pi) * 384 + gj * 16 + pj];
    #pragma unroll
    for (int o = 32; o > 0; o >>= 1) v += __shfl_down(v, o);
    __shared__ float red[4];
    if ((tid & 63) == 0) red[tid >> 6] = v;
    __syncthreads();
    if (tid == 0) pooled[bp] = (red[0] + red[1] + red[2] + red[3]) * (1.0f / 256.0f);
}

// ---------------- exact stable top-k via rank counting ----------------
__global__ __launch_bounds__(576) void topk_kernel(const float* __restrict__ pooled,
                                                   int* __restrict__ idxsel) {
    __shared__ float a[NPATCH];
    int b = blockIdx.x, tid = threadIdx.x;
    a[tid] = fabsf(pooled[b * NPATCH + tid]);
    __syncthreads();
    float mine = a[tid];
    int rank = 0;
    for (int j = 0; j < NPATCH; ++j) {
        float aj = a[j];
        rank += (aj > mine) || (aj == mine && j < tid);
    }
    if (rank < KSEL) idxsel[b * KSEL + rank] = tid;
}

// ---------------- fp32 -> bf16 straight convert ----------------
__global__ __launch_bounds__(256) void convert_bf16(const float* __restrict__ in,
                                                    __hip_bfloat16* __restrict__ out,
                                                    int n) {
    int i = blockIdx.x * 256 + threadIdx.x;
    if (i < n) out[i] = __float2bfloat16(in[i]);
}

// ---------------- all 4 layer weights: fp32 [K][N] -> bf16 [N][K], one launch ----------------
__global__ __launch_bounds__(256) void convert_layer(const float* __restrict__ wqkv,
                                                     const float* __restrict__ wo,
                                                     const float* __restrict__ w1,
                                                     const float* __restrict__ w2,
                                                     __hip_bfloat16* __restrict__ oqkv,
                                                     __hip_bfloat16* __restrict__ owo,
                                                     __hip_bfloat16* __restrict__ ow1,
                                                     __hip_bfloat16* __restrict__ ow2) {
    __shared__ float tb[32][33];
    int bid = blockIdx.x;
    const float* W; __hip_bfloat16* O; int K, N, tile;
    if (bid < 1728)      { W = wqkv; O = oqkv; K = 768;  N = 2304; tile = bid; }
    else if (bid < 2304) { W = wo;   O = owo;  K = 768;  N = 768;  tile = bid - 1728; }
    else if (bid < 4608) { W = w1;   O = ow1;  K = 768;  N = 3072; tile = bid - 2304; }
    else                 { W = w2;   O = ow2;  K = 3072; N = 768;  tile = bid - 4608; }
    int ntx = N >> 5;
    int n0 = (tile % ntx) << 5, k0 = (tile / ntx) << 5;
    int t = threadIdx.x;
    int r = t >> 3, c = (t & 7) << 2;
    float4 v = *(const float4*)&W[(size_t)(k0 + r) * N + n0 + c];
    tb[r][c] = v.x; tb[r][c + 1] = v.y; tb[r][c + 2] = v.z; tb[r][c + 3] = v.w;
    __syncthreads();
    int n = t >> 3, k = (t & 7) << 2;
    __hip_bfloat16* dst = &O[(size_t)(n0 + n) * K + k0 + k];
    #pragma unroll
    for (int j = 0; j < 4; ++j) dst[j] = __float2bfloat16(tb[k + j][n]);
}

// ---------------- im2col of SELECTED patches only (bf16 out) ----------------
__global__ __launch_bounds__(256) void im2col_kernel(const float* __restrict__ x,
                                                     const int* __restrict__ idxsel,
                                                     __hip_bfloat16* __restrict__ col) {
    int t = blockIdx.x;
    int b = t / KSEL, r = t - b * KSEL;
    int p = idxsel[b * KSEL + r];
    int gi = p / 24, gj = p - gi * 24;
    int tid = threadIdx.x;
    int pi = tid >> 4, pj = tid & 15;
    __hip_bfloat16* crow = col + (size_t)t * 768;
    #pragma unroll
    for (int c = 0; c < 3; ++c)
        crow[c * 256 + tid] = __float2bfloat16(
            x[((size_t)(b * 3 + c) * 384 + gi * 16 + pi) * 384 + gj * 16 + pj]);
}

// ---------------- assemble h: cls + selected tokens + pos_emb (fp32) ----------------
__global__ __launch_bounds__(256) void assemble_tokens(const float* __restrict__ temp,
                                                       const float* __restrict__ cls_tok,
                                                       const float* __restrict__ pos_emb,
                                                       const int* __restrict__ idxsel,
                                                       float* __restrict__ h) {
    int row = blockIdx.x;
    int b = row / SS, s = row - b * SS;
    int tid = threadIdx.x;
    float* hrow = h + (size_t)row * DD;
    if (s == 0) {
        #pragma unroll
        for (int c = 0; c < 3; ++c) {
            int j = c * 256 + tid;
            hrow[j] = cls_tok[j] + pos_emb[j];
        }
    } else {
        int r = s - 1;
        int p = idxsel[b * KSEL + r];
        const float* trow = temp + (size_t)(b * KSEL + r) * DD;
        const float* pe = pos_emb + (size_t)(1 + p) * DD;
        #pragma unroll
        for (int c = 0; c < 3; ++c) {
            int j = c * 256 + tid;
            hrow[j] = trow[j] + pe[j];
        }
    }
}

// ---------------- LayerNorm over 768, templated output dtype ----------------
template <typename T>
__global__ __launch_bounds__(256) void ln_kernel(const float* __restrict__ in,
                                                 T* __restrict__ out,
                                                 const float* __restrict__ g,
                                                 const float* __restrict__ be,
                                                 size_t in_stride) {
    int row = blockIdx.x;
    const float* r = in + (size_t)row * in_stride;
    T* w = out + (size_t)row * DD;
    int tid = threadIdx.x;
    float v0 = r[tid], v1 = r[256 + tid], v2 = r[512 + tid];
    float s = v0 + v1 + v2;
    #pragma unroll
    for (int o = 32; o > 0; o >>= 1) s += __shfl_down(s, o);
    __shared__ float red[4];
    if ((tid & 63) == 0) red[tid >> 6] = s;
    __syncthreads();
    float mu = (red[0] + red[1] + red[2] + red[3]) * (1.0f / 768.0f);
    float d0 = v0 - mu, d1 = v1 - mu, d2 = v2 - mu;
    float q = d0 * d0 + d1 * d1 + d2 * d2;
    #pragma unroll
    for (int o = 32; o > 0; o >>= 1) q += __shfl_down(q, o);
    __syncthreads();
    if ((tid & 63) == 0) red[tid >> 6] = q;
    __syncthreads();
    float var = (red[0] + red[1] + red[2] + red[3]) * (1.0f / 768.0f);
    float rs = rsqrtf(var + 1e-6f);
    store_val(&w[tid],       d0 * rs * g[tid]       + be[tid]);
    store_val(&w[256 + tid], d1 * rs * g[256 + tid] + be[256 + tid]);
    store_val(&w[512 + tid], d2 * rs * g[512 + tid] + be[512 + tid]);
}

// ---------------- bf16 MFMA GEMM: C = A[M][K] @ BT[N][K]^T ----------------
// 128x128 tile, BK=32, 4 waves, global_load_lds w=16, LDS XOR swizzle (both sides),
// depth-2 pipelined: 3 LDS buffers, counted s_waitcnt vmcnt(4), raw s_barrier.
// XCD-chunked bijective block swizzle for A-panel L2 reuse.
template <typename OUT_T, int ACT, int RES>
__global__ __launch_bounds__(256) void gemm_bf16(const __hip_bfloat16* __restrict__ A,
                                                 const __hip_bfloat16* __restrict__ BT,
                                                 OUT_T* __restrict__ C,
                                                 const float* __restrict__ bias,
                                                 const float* __restrict__ res,
                                                 int M, int N, int K) {
    __shared__ __hip_bfloat16 smA[3][128 * 32];
    __shared__ __hip_bfloat16 smB[3][128 * 32];
    const int t = threadIdx.x;
    const int lane = t & 63, wid = t >> 6;
    const int wr = wid >> 1, wc = wid & 1;        // 2x2 waves, 64x64 each
    const int l15 = lane & 15, l4 = lane >> 4;

    // XCD-chunked bijective swizzle over row-major linear block id (m204)
    const int gx = gridDim.x;
    const int nwg = gx * gridDim.y;
    const int orig = blockIdx.y * gx + blockIdx.x;
    const int q8 = nwg >> 3, r8 = nwg & 7;
    const int xcd = orig & 7, linb = orig >> 3;
    const int swz = (xcd < r8 ? xcd * (q8 + 1) : r8 * (q8 + 1) + (xcd - r8) * q8) + linb;
    const int m0 = (swz / gx) << 7;
    const int n0 = (swz - (swz / gx) * gx) << 7;

    // fragment read byte offsets within one 8KB buffer (swizzled)
    int ra[4], rb[4];
    #pragma unroll
    for (int f = 0; f < 4; ++f) {
        int ml = wr * 64 + f * 16 + l15;
        ra[f] = ml * 64 + ((l4 ^ ((ml >> 1) & 3)) << 4);
        int nl = wc * 64 + f * 16 + l15;
        rb[f] = nl * 64 + ((l4 ^ ((nl >> 1) & 3)) << 4);
    }

    // staging source element offsets (inverse swizzle), 2 slots/thread each
    size_t aoff[2], boff[2];
    #pragma unroll
    for (int it = 0; it < 2; ++it) {
        int s = it * 256 + t;
        int m = s >> 2;
        int kc = (s & 3) ^ ((m >> 1) & 3);
        int gm = m0 + m; if (gm > M - 1) gm = M - 1;
        aoff[it] = (size_t)gm * K + kc * 8;
        boff[it] = (size_t)(n0 + m) * K + kc * 8;
    }
    const int wb = wid << 10;                      // wave-uniform LDS base

    auto STAGE = [&](int kt, int buf) {
        int k0e = kt << 5;
        gload16(A + aoff[0] + k0e, (char*)(&smA[buf][0]) + wb);
        gload16(A + aoff[1] + k0e, (char*)(&smA[buf][0]) + wb + 4096);
        gload16(BT + boff[0] + k0e, (char*)(&smB[buf][0]) + wb);
        gload16(BT + boff[1] + k0e, (char*)(&smB[buf][0]) + wb + 4096);
    };

    f32x4 acc[4][4];
    #pragma unroll
    for (int i = 0; i < 4; ++i)
        #pragma unroll
        for (int j = 0; j < 4; ++j) acc[i][j] = (f32x4){0.f, 0.f, 0.f, 0.f};

    const int nt = K >> 5;
    STAGE(0, 0);
    STAGE(1, 1);
    int cur = 0, stb = 2;
    for (int kt = 0; kt < nt; ++kt) {
        if (kt + 1 < nt) { asm volatile("s_waitcnt vmcnt(4)" ::: "memory"); }
        else             { asm volatile("s_waitcnt vmcnt(0)" ::: "memory"); }
        __builtin_amdgcn_s_barrier();
        __builtin_amdgcn_sched_barrier(0);
        if (kt + 2 < nt) STAGE(kt + 2, stb);
        const char* sa = (const char*)(&smA[cur][0]);
        const char* sb = (const char*)(&smB[cur][0]);
        bf16x8 af[4], bf[4];
        #pragma unroll
        for (int f = 0; f < 4; ++f) {
            af[f] = *(const bf16x8*)(sa + ra[f]);
            bf[f] = *(const bf16x8*)(sb + rb[f]);
        }
        #pragma unroll
        for (int i = 0; i < 4; ++i)
            #pragma unroll
            for (int j = 0; j < 4; ++j)
                acc[i][j] = __builtin_amdgcn_mfma_f32_16x16x32_bf16(af[i], bf[j], acc[i][j], 0, 0, 0);
        cur = cur == 2 ? 0 : cur + 1;
        stb = stb == 2 ? 0 : stb + 1;
    }

    // epilogue: bias / gelu / residual, fp32 math, templated store
    #pragma unroll
    for (int i = 0; i < 4; ++i) {
        int gmb = m0 + wr * 64 + i * 16 + l4 * 4;
        #pragma unroll
        for (int j = 0; j < 4; ++j) {
            int gn = n0 + wc * 64 + j * 16 + l15;
            float bv = bias ? bias[gn] : 0.f;
            #pragma unroll
            for (int r = 0; r < 4; ++r) {
                int gm = gmb + r;
                if (gm < M) {
                    float v = acc[i][j][r] + bv;
                    if (ACT) v = gelu_f(v);
                    if (RES) v += res[(size_t)gm * N + gn];
                    store_val(&C[(size_t)gm * N + gn], v);
                }
            }
        }
    }
}

// ---------------- fused flash attention (bf16 MFMA, 1 wave per block) ----------------
// grid (10 q-tiles, B*NH). qkv bf16 [4624][2304]; out bf16 [4624][768].
__global__ __launch_bounds__(64) void attn_fused(const __hip_bfloat16* __restrict__ qkv,
                                                 __hip_bfloat16* __restrict__ o) {
    __shared__ __hip_bfloat16 p_lds[32][40];   // P repack bounce (row=q-local, col=key-local)
    __shared__ __hip_bfloat16 v_lds[32][68];   // V tile, padded rows (136B) for transposed reads
    const int qt = blockIdx.x, bh = blockIdx.y;
    const int b = bh / NHD, hd = bh - b * NHD;
    const int lane = threadIdx.x;
    const int l15 = lane & 15, l4 = lane >> 4;
    const size_t tb = (size_t)b * SS;
    const int hc = hd * 64;

    // Q fragments: aq[qi][kd], A-layout (lane row = l15, head-dim chunk = l4*8)
    bf16x8 aq[2][2];
    #pragma unroll
    for (int qi = 0; qi < 2; ++qi) {
        int qr = qt * 32 + qi * 16 + l15;
        if (qr >= SS) qr = SS - 1;
        const __hip_bfloat16* qrow = qkv + (tb + qr) * 2304 + hc;
        #pragma unroll
        for (int kd = 0; kd < 2; ++kd)
            aq[qi][kd] = *(const bf16x8*)(qrow + kd * 32 + l4 * 8);
    }

    float m_run[2][4], l_run[2][4];
    f32x4 oa[2][4];
    #pragma unroll
    for (int qi = 0; qi < 2; ++qi)
        #pragma unroll
        for (int r = 0; r < 4; ++r) { m_run[qi][r] = -1e30f; l_run[qi][r] = 0.f; }
    #pragma unroll
    for (int qi = 0; qi < 2; ++qi)
        #pragma unroll
        for (int dt = 0; dt < 4; ++dt) oa[qi][dt] = (f32x4){0.f, 0.f, 0.f, 0.f};

    for (int kt = 0; kt < 10; ++kt) {
        const int kbase = kt * 32;
        // V tile global loads (issue early; 8B per lane per row-quad)
        bf16x4 vreg[8];
        #pragma unroll
        for (int it = 0; it < 8; ++it) {
            int vr = kbase + it * 4 + l4;
            if (vr >= SS) vr = SS - 1;
            vreg[it] = *(const bf16x4*)(qkv + (tb + vr) * 2304 + 1536 + hc + l15 * 4);
        }
        // K fragments: bk[ki][kd], B-layout (lane col = key l15, head-dim chunk l4*8)
        bf16x8 bk[2][2];
        #pragma unroll
        for (int ki = 0; ki < 2; ++ki) {
            int kr = kbase + ki * 16 + l15;
            if (kr >= SS) kr = SS - 1;
            const __hip_bfloat16* krow = qkv + (tb + kr) * 2304 + 768 + hc;
            #pragma unroll
            for (int kd = 0; kd < 2; ++kd)
                bk[ki][kd] = *(const bf16x8*)(krow + kd * 32 + l4 * 8);
        }
        // S = Q K^T (C-layout: row q = l4*4+r, col key = l15)
        f32x4 s[2][2];
        #pragma unroll
        for (int qi = 0; qi < 2; ++qi)
            #pragma unroll
            for (int ki = 0; ki < 2; ++ki) {
                f32x4 a = (f32x4){0.f, 0.f, 0.f, 0.f};
                #pragma unroll
                for (int kd = 0; kd < 2; ++kd)
                    a = __builtin_amdgcn_mfma_f32_16x16x32_bf16(aq[qi][kd], bk[ki][kd], a, 0, 0, 0);
                s[qi][ki] = a;
            }
        // scale + key masking
        #pragma unroll
        for (int ki = 0; ki < 2; ++ki) {
            bool valid = (kbase + ki * 16 + l15) < SS;
            #pragma unroll
            for (int qi = 0; qi < 2; ++qi)
                #pragma unroll
                for (int r = 0; r < 4; ++r)
                    s[qi][ki][r] = valid ? s[qi][ki][r] * 0.125f : -1e30f;
        }
        // online softmax (row stats across the 16 l15 lanes of each l4 group)
        float p[2][2][4];
        #pragma unroll
        for (int qi = 0; qi < 2; ++qi) {
            float tm[4];
            #pragma unroll
            for (int r = 0; r < 4; ++r) tm[r] = fmaxf(s[qi][0][r], s[qi][1][r]);
            #pragma unroll
            for (int sh = 1; sh < 16; sh <<= 1)
                #pragma unroll
                for (int r = 0; r < 4; ++r) tm[r] = fmaxf(tm[r], __shfl_xor(tm[r], sh));
            float rs[4];
            #pragma unroll
            for (int r = 0; r < 4; ++r) {
                float mn = fmaxf(m_run[qi][r], tm[r]);
                float corr = __expf(m_run[qi][r] - mn);
                m_run[qi][r] = mn;
                float p0 = __expf(s[qi][0][r] - mn);
                float p1 = __expf(s[qi][1][r] - mn);
                p[qi][0][r] = p0; p[qi][1][r] = p1;
                rs[r] = p0 + p1;
                l_run[qi][r] *= corr;
                #pragma unroll
                for (int dt = 0; dt < 4; ++dt) oa[qi][dt][r] *= corr;
            }
            #pragma unroll
            for (int sh = 1; sh < 16; sh <<= 1)
                #pragma unroll
                for (int r = 0; r < 4; ++r) rs[r] += __shfl_xor(rs[r], sh);
            #pragma unroll
            for (int r = 0; r < 4; ++r) l_run[qi][r] += rs[r];
        }
        // P -> LDS (C-layout positions), V -> LDS (row-major, padded)
        #pragma unroll
        for (int qi = 0; qi < 2; ++qi)
            #pragma unroll
            for (int ki = 0; ki < 2; ++ki)
                #pragma unroll
                for (int r = 0; r < 4; ++r)
                    p_lds[qi * 16 + l4 * 4 + r][ki * 16 + l15] = __float2bfloat16(p[qi][ki][r]);
        #pragma unroll
        for (int it = 0; it < 8; ++it)
            *(bf16x4*)&v_lds[it * 4 + l4][l15 * 4] = vreg[it];
        __syncthreads();
        // P as A-operand, V^T as B-operand
        bf16x8 pa[2];
        #pragma unroll
        for (int qi = 0; qi < 2; ++qi)
            pa[qi] = *(const bf16x8*)&p_lds[qi * 16 + l15][l4 * 8];
        bf16x8 vb[4];
        #pragma unroll
        for (int dt = 0; dt < 4; ++dt) {
            bf16x8 v;
            #pragma unroll
            for (int j = 0; j < 8; ++j)
                v[j] = *(const short*)&v_lds[l4 * 8 + j][dt * 16 + l15];
            vb[dt] = v;
        }
        #pragma unroll
        for (int qi = 0; qi < 2; ++qi)
            #pragma unroll
            for (int dt = 0; dt < 4; ++dt)
                oa[qi][dt] = __builtin_amdgcn_mfma_f32_16x16x32_bf16(pa[qi], vb[dt], oa[qi][dt], 0, 0, 0);
        __syncthreads();
    }
    // normalize + store
    #pragma unroll
    for (int qi = 0; qi < 2; ++qi)
        #pragma unroll
        for (int r = 0; r < 4; ++r) {
            int q = qt * 32 + qi * 16 + l4 * 4 + r;
            if (q < SS) {
                float inv = 1.0f / l_run[qi][r];
                __hip_bfloat16* orow = o + (tb + q) * 768 + hc;
                #pragma unroll
                for (int dt = 0; dt < 4; ++dt)
                    orow[dt * 16 + l15] = __float2bfloat16(oa[qi][dt][r] * inv);
            }
        }
}

// ---------------- fp32 GEMM (head only: 16x1000x768) ----------------
__global__ __launch_bounds__(256) void gemm_f32(const float* __restrict__ A,
                                                const float* __restrict__ Bm,
                                                float* __restrict__ Cm,
                                                const float* __restrict__ bias,
                                                int M, int N, int Kd) {
    __shared__ float As[16][68];
    __shared__ float Bs[16][64];
    int tid = threadIdx.x;
    int m0 = blockIdx.y << 6;
    int n0 = blockIdx.x << 6;
    int tx = tid & 15, ty = tid >> 4;
    int arow = tid >> 2, acol = (tid & 3) << 2;
    int brow = tid >> 4, bcol = (tid & 15) << 2;
    float acc[4][4] = {};
    for (int k0 = 0; k0 < Kd; k0 += 16) {
        float4 av = make_float4(0.f, 0.f, 0.f, 0.f);
        int gm = m0 + arow;
        if (gm < M) av = *(const float4*)&A[(size_t)gm * Kd + k0 + acol];
        As[acol + 0][arow] = av.x;
        As[acol + 1][arow] = av.y;
        As[acol + 2][arow] = av.z;
        As[acol + 3][arow] = av.w;
        float4 bv = make_float4(0.f, 0.f, 0.f, 0.f);
        int gn = n0 + bcol;
        const float* brp = &Bm[(size_t)(k0 + brow) * N];
        if (gn + 3 < N) bv = *(const float4*)&brp[gn];
        else if (gn < N) {
            bv.x = brp[gn];
            if (gn + 1 < N) bv.y = brp[gn + 1];
            if (gn + 2 < N) bv.z = brp[gn + 2];
        }
        *(float4*)&Bs[brow][bcol] = bv;
        __syncthreads();
        #pragma unroll
        for (int kk = 0; kk < 16; ++kk) {
            float a[4], b[4];
            *(float4*)a = *(const float4*)&As[kk][ty << 2];
            *(float4*)b = *(const float4*)&Bs[kk][tx << 2];
            #pragma unroll
            for (int i = 0; i < 4; ++i)
                #pragma unroll
                for (int j = 0; j < 4; ++j)
                    acc[i][j] = fmaf(a[i], b[j], acc[i][j]);
        }
        __syncthreads();
    }
    #pragma unroll
    for (int i = 0; i < 4; ++i) {
        int gm = m0 + (ty << 2) + i;
        if (gm >= M) continue;
        #pragma unroll
        for (int j = 0; j < 4; ++j) {
            int gn = n0 + (tx << 2) + j;
            if (gn >= N) continue;
            Cm[(size_t)gm * N + gn] = acc[i][j] + (bias ? bias[gn] : 0.f);
        }
    }
}

// ---------------- workspace layout (float offsets) ----------------
static const size_t OFF_POOLED = 0;           //  9216 f
static const size_t OFF_IDX    = 10240;       //  4608 int
static const size_t OFF_H      = 16384;       //  3,551,232 f
static const size_t OFF_YB     = 3567616;     //  3,551,232 bf16 (1,775,616 f)
static const size_t OFF_OB     = 5343232;     //  3,551,232 bf16
static const size_t OFF_QKVB   = 7118848;     // 10,653,696 bf16 (5,326,848 f)
static const size_t OFF_WBUF   = 12445696;    //  7,077,888 bf16 (3,538,944 f)
static const size_t OFF_PWB    = 15984640;    //    589,824 bf16 (294,912 f)
static const size_t OFF_YF     = 16279552;    //     12,288 f
static const size_t OFF_BIG    = 16291840;    //  7,102,464 f (col+temp / hidden)
// total 23,394,304 floats = 93.6 MB

extern "C" void kernel_launch(void* const* d_in, const int* in_sizes, int n_in,
                              void* d_out, int out_size, void* d_ws, size_t ws_size,
                              hipStream_t stream) {
    const float* x       = (const float*)d_in[0];
    const float* patch_w = (const float*)d_in[1];
    const float* patch_b = (const float*)d_in[2];
    const float* cls_tok = (const float*)d_in[3];
    const float* pos_emb = (const float*)d_in[4];
    const float* ln1_g   = (const float*)d_in[5];
    const float* ln1_b   = (const float*)d_in[6];
    const float* Wqkv    = (const float*)d_in[7];
    const float* bqkv    = (const float*)d_in[8];
    const float* Wo      = (const float*)d_in[9];
    const float* bo      = (const float*)d_in[10];
    const float* ln2_g   = (const float*)d_in[11];
    const float* ln2_b   = (const float*)d_in[12];
    const float* W1      = (const float*)d_in[13];
    const float* b1      = (const float*)d_in[14];
    const float* W2      = (const float*)d_in[15];
    const float* b2      = (const float*)d_in[16];
    const float* lnf_g   = (const float*)d_in[17];
    const float* lnf_b   = (const float*)d_in[18];
    const float* fc_w    = (const float*)d_in[19];
    const float* fc_b    = (const float*)d_in[20];
    float* out = (float*)d_out;
    float* ws  = (float*)d_ws;

    float*          pooled = ws + OFF_POOLED;
    int*            idxsel = (int*)(ws + OFF_IDX);
    float*          h      = ws + OFF_H;
    __hip_bfloat16* yb     = (__hip_bfloat16*)(ws + OFF_YB);
    __hip_bfloat16* ob     = (__hip_bfloat16*)(ws + OFF_OB);
    __hip_bfloat16* qkvb   = (__hip_bfloat16*)(ws + OFF_QKVB);
    __hip_bfloat16* wbuf   = (__hip_bfloat16*)(ws + OFF_WBUF);
    __hip_bfloat16* pwb    = (__hip_bfloat16*)(ws + OFF_PWB);
    float*          yf     = ws + OFF_YF;
    float*          big    = ws + OFF_BIG;
    __hip_bfloat16* col    = (__hip_bfloat16*)big;             // 3,538,944 bf16
    float*          temp   = big + 1769472;                    // 3,538,944 f
    __hip_bfloat16* hidden = (__hip_bfloat16*)big;             // 14,204,928 bf16

    __hip_bfloat16* wqkvT = wbuf;                              // [2304][768]
    __hip_bfloat16* woT   = wbuf + 1769472;                    // [768][768]
    __hip_bfloat16* w1T   = wbuf + 2359296;                    // [3072][768]
    __hip_bfloat16* w2T   = wbuf + 4718592;                    // [768][3072]

    // ---- sparse selection + patch embedding ----
    pool_kernel<<<BB * NPATCH, 256, 0, stream>>>(x, pooled);
    topk_kernel<<<BB, 576, 0, stream>>>(pooled, idxsel);
    convert_bf16<<<(589824 + 255) / 256, 256, 0, stream>>>(patch_w, pwb, 589824);
    im2col_kernel<<<BB * KSEL, 256, 0, stream>>>(x, idxsel, col);
    gemm_bf16<float, 0, 0><<<dim3(6, 36), 256, 0, stream>>>(col, pwb, temp, patch_b,
                                                            nullptr, 4608, DD, DD);
    assemble_tokens<<<BB * SS, 256, 0, stream>>>(temp, cls_tok, pos_emb, idxsel, h);

    const int M = BB * SS;            // 4624
    const int MG = 37;                // ceil(4624/128)

    // ---- transformer layers ----
    for (int i = 0; i < NLAY; ++i) {
        convert_layer<<<6912, 256, 0, stream>>>(Wqkv + (size_t)i * DD * 3 * DD,
                                                Wo + (size_t)i * DD * DD,
                                                W1 + (size_t)i * DD * FFD,
                                                W2 + (size_t)i * FFD * DD,
                                                wqkvT, woT, w1T, w2T);

        ln_kernel<__hip_bfloat16><<<M, 256, 0, stream>>>(h, yb, ln1_g + i * DD, ln1_b + i * DD, DD);
        gemm_bf16<__hip_bfloat16, 0, 0><<<dim3(18, MG), 256, 0, stream>>>(
            yb, wqkvT, qkvb, bqkv + (size_t)i * 3 * DD, nullptr, M, 3 * DD, DD);
        attn_fused<<<dim3(10, BB * NHD), 64, 0, stream>>>(qkvb, ob);
        gemm_bf16<float, 0, 1><<<dim3(6, MG), 256, 0, stream>>>(
            ob, woT, h, bo + (size_t)i * DD, h, M, DD, DD);
        ln_kernel<__hip_bfloat16><<<M, 256, 0, stream>>>(h, yb, ln2_g + i * DD, ln2_b + i * DD, DD);
        gemm_bf16<__hip_bfloat16, 1, 0><<<dim3(24, MG), 256, 0, stream>>>(
            yb, w1T, hidden, b1 + (size_t)i * FFD, nullptr, M, FFD, DD);
        gemm_bf16<float, 0, 1><<<dim3(6, MG), 256, 0, stream>>>(
            hidden, w2T, h, b2 + (size_t)i * DD, h, M, DD, FFD);
    }

    // ---- final LN on cls token + fp32 classifier head ----
    ln_kernel<float><<<BB, 256, 0, stream>>>(h, yf, lnf_g, lnf_b, (size_t)SS * DD);
    gemm_f32<<<dim3(16, 1), 256, 0, stream>>>(yf, fc_w, out, fc_b, BB, 1000, DD);
}

// Round 4
// 3008.070 us; speedup vs baseline: 4.7419x; 1.1356x over previous
//
#include <hip/hip_runtime.h>
#include <hip/hip_bf16.h>
#include <math.h>

// ---------------- problem constants ----------------
#define BB 16
#define SS 289          // 1 cls + 288 selected tokens
#define DD 768
#define FFD 3072
#define NHD 12
#define NLAY 12
#define KSEL 288
#define NPATCH 576

typedef short bf16x8 __attribute__((ext_vector_type(8)));
typedef short bf16x4 __attribute__((ext_vector_type(4)));
typedef float f32x4 __attribute__((ext_vector_type(4)));

typedef __attribute__((address_space(3))) void lds_t;
typedef __attribute__((address_space(1))) const void glb_t;

__device__ __forceinline__ void gload16(const void* g, void* l) {
    __builtin_amdgcn_global_load_lds((glb_t*)g, (lds_t*)l, 16, 0, 0);
}

// inline-asm LDS read: invisible to compiler alias analysis, so no auto
// vmcnt(0) drain against outstanding global_load_lds (rule #18 discipline:
// caller must s_waitcnt lgkmcnt(0) + sched_barrier(0) before consuming).
__device__ __forceinline__ bf16x8 ds_read128(unsigned addr) {
    bf16x8 r;
    asm volatile("ds_read_b128 %0, %1" : "=v"(r) : "v"(addr));
    return r;
}

__device__ __forceinline__ float gelu_f(float v) {
    return 0.5f * v * (1.0f + erff(v * 0.70710678118654752f));
}

__device__ __forceinline__ void store_val(float* p, float v) { *p = v; }
__device__ __forceinline__ void store_val(__hip_bfloat16* p, float v) { *p = __float2bfloat16(v); }

// ---------------- patch pooling (channel 0, 16x16 mean) ----------------
__global__ __launch_bounds__(256) void pool_kernel(const float* __restrict__ x,
                                                   float* __restrict__ pooled) {
    int bp = blockIdx.x;
    int b = bp / NPATCH, p = bp - b * NPATCH;
    int gi = p / 24, gj = p - gi * 24;
    int tid = threadIdx.x;
    int pi = tid >> 4, pj = tid & 15;
    float v = x[((size_t)(b * 3) * 384 + gi * 16 + pi) * 384 + gj * 16 + pj];
    #pragma unroll
    for (int o = 32; o > 0; o >>= 1) v += __shfl_down(v, o);
    __shared__ float red[4];
    if ((tid & 63) == 0) red[tid >> 6] = v;
    __syncthreads();
    if (tid == 0) pooled[bp] = (red[0] + red[1] + red[2] + red[3]) * (1.0f / 256.0f);
}

// ---------------- exact stable top-k via rank counting ----------------
__global__ __launch_bounds__(576) void topk_kernel(const float* __restrict__ pooled,
                                                   int* __restrict__ idxsel) {
    __shared__ float a[NPATCH];
    int b = blockIdx.x, tid = threadIdx.x;
    a[tid] = fabsf(pooled[b * NPATCH + tid]);
    __syncthreads();
    float mine = a[tid];
    int rank = 0;
    for (int j = 0; j < NPATCH; ++j) {
        float aj = a[j];
        rank += (aj > mine) || (aj == mine && j < tid);
    }
    if (rank < KSEL) idxsel[b * KSEL + rank] = tid;
}

// ---------------- fp32 -> bf16 straight convert ----------------
__global__ __launch_bounds__(256) void convert_bf16(const float* __restrict__ in,
                                                    __hip_bfloat16* __restrict__ out,
                                                    int n) {
    int i = blockIdx.x * 256 + threadIdx.x;
    if (i < n) out[i] = __float2bfloat16(in[i]);
}

// ---------------- all 4 layer weights: fp32 [K][N] -> bf16 [N][K], one launch ----------------
__global__ __launch_bounds__(256) void convert_layer(const float* __restrict__ wqkv,
                                                     const float* __restrict__ wo,
                                                     const float* __restrict__ w1,
                                                     const float* __restrict__ w2,
                                                     __hip_bfloat16* __restrict__ oqkv,
                                                     __hip_bfloat16* __restrict__ owo,
                                                     __hip_bfloat16* __restrict__ ow1,
                                                     __hip_bfloat16* __restrict__ ow2) {
    __shared__ float tb[32][33];
    int bid = blockIdx.x;
    const float* W; __hip_bfloat16* O; int K, N, tile;
    if (bid < 1728)      { W = wqkv; O = oqkv; K = 768;  N = 2304; tile = bid; }
    else if (bid < 2304) { W = wo;   O = owo;  K = 768;  N = 768;  tile = bid - 1728; }
    else if (bid < 4608) { W = w1;   O = ow1;  K = 768;  N = 3072; tile = bid - 2304; }
    else                 { W = w2;   O = ow2;  K = 3072; N = 768;  tile = bid - 4608; }
    int ntx = N >> 5;
    int n0 = (tile % ntx) << 5, k0 = (tile / ntx) << 5;
    int t = threadIdx.x;
    int r = t >> 3, c = (t & 7) << 2;
    float4 v = *(const float4*)&W[(size_t)(k0 + r) * N + n0 + c];
    tb[r][c] = v.x; tb[r][c + 1] = v.y; tb[r][c + 2] = v.z; tb[r][c + 3] = v.w;
    __syncthreads();
    int n = t >> 3, k = (t & 7) << 2;
    __hip_bfloat16* dst = &O[(size_t)(n0 + n) * K + k0 + k];
    #pragma unroll
    for (int j = 0; j < 4; ++j) dst[j] = __float2bfloat16(tb[k + j][n]);
}

// ---------------- im2col of SELECTED patches only (bf16 out) ----------------
__global__ __launch_bounds__(256) void im2col_kernel(const float* __restrict__ x,
                                                     const int* __restrict__ idxsel,
                                                     __hip_bfloat16* __restrict__ col) {
    int t = blockIdx.x;
    int b = t / KSEL, r = t - b * KSEL;
    int p = idxsel[b * KSEL + r];
    int gi = p / 24, gj = p - gi * 24;
    int tid = threadIdx.x;
    int pi = tid >> 4, pj = tid & 15;
    __hip_bfloat16* crow = col + (size_t)t * 768;
    #pragma unroll
    for (int c = 0; c < 3; ++c)
        crow[c * 256 + tid] = __float2bfloat16(
            x[((size_t)(b * 3 + c) * 384 + gi * 16 + pi) * 384 + gj * 16 + pj]);
}

// ---------------- assemble h: cls + selected tokens + pos_emb (fp32) ----------------
__global__ __launch_bounds__(256) void assemble_tokens(const float* __restrict__ temp,
                                                       const float* __restrict__ cls_tok,
                                                       const float* __restrict__ pos_emb,
                                                       const int* __restrict__ idxsel,
                                                       float* __restrict__ h) {
    int row = blockIdx.x;
    int b = row / SS, s = row - b * SS;
    int tid = threadIdx.x;
    float* hrow = h + (size_t)row * DD;
    if (s == 0) {
        #pragma unroll
        for (int c = 0; c < 3; ++c) {
            int j = c * 256 + tid;
            hrow[j] = cls_tok[j] + pos_emb[j];
        }
    } else {
        int r = s - 1;
        int p = idxsel[b * KSEL + r];
        const float* trow = temp + (size_t)(b * KSEL + r) * DD;
        const float* pe = pos_emb + (size_t)(1 + p) * DD;
        #pragma unroll
        for (int c = 0; c < 3; ++c) {
            int j = c * 256 + tid;
            hrow[j] = trow[j] + pe[j];
        }
    }
}

// ---------------- LayerNorm over 768, templated output dtype ----------------
template <typename T>
__global__ __launch_bounds__(256) void ln_kernel(const float* __restrict__ in,
                                                 T* __restrict__ out,
                                                 const float* __restrict__ g,
                                                 const float* __restrict__ be,
                                                 size_t in_stride) {
    int row = blockIdx.x;
    const float* r = in + (size_t)row * in_stride;
    T* w = out + (size_t)row * DD;
    int tid = threadIdx.x;
    float v0 = r[tid], v1 = r[256 + tid], v2 = r[512 + tid];
    float s = v0 + v1 + v2;
    #pragma unroll
    for (int o = 32; o > 0; o >>= 1) s += __shfl_down(s, o);
    __shared__ float red[4];
    if ((tid & 63) == 0) red[tid >> 6] = s;
    __syncthreads();
    float mu = (red[0] + red[1] + red[2] + red[3]) * (1.0f / 768.0f);
    float d0 = v0 - mu, d1 = v1 - mu, d2 = v2 - mu;
    float q = d0 * d0 + d1 * d1 + d2 * d2;
    #pragma unroll
    for (int o = 32; o > 0; o >>= 1) q += __shfl_down(q, o);
    __syncthreads();
    if ((tid & 63) == 0) red[tid >> 6] = q;
    __syncthreads();
    float var = (red[0] + red[1] + red[2] + red[3]) * (1.0f / 768.0f);
    float rs = rsqrtf(var + 1e-6f);
    store_val(&w[tid],       d0 * rs * g[tid]       + be[tid]);
    store_val(&w[256 + tid], d1 * rs * g[256 + tid] + be[256 + tid]);
    store_val(&w[512 + tid], d2 * rs * g[512 + tid] + be[512 + tid]);
}

// ---------------- bf16 MFMA GEMM: C = A[M][K] @ BT[N][K]^T ----------------
// 128x128 tile, BK=32, 4 waves, global_load_lds w=16, LDS XOR swizzle (both sides).
// Depth-3 pipeline: 4 LDS buffers (64KB), counted s_waitcnt vmcnt(8), raw s_barrier,
// inline-asm ds_read_b128 (avoids compiler-inserted vmcnt(0) alias drain),
// explicit lgkmcnt(0)+sched_barrier(0) before MFMA (rule #18).
// XCD-chunked bijective block swizzle for L2 reuse.
template <typename OUT_T, int ACT, int RES>
__global__ __launch_bounds__(256) void gemm_bf16(const __hip_bfloat16* __restrict__ A,
                                                 const __hip_bfloat16* __restrict__ BT,
                                                 OUT_T* __restrict__ C,
                                                 const float* __restrict__ bias,
                                                 const float* __restrict__ res,
                                                 int M, int N, int K) {
    __shared__ __hip_bfloat16 smA[4][128 * 32];   // 4 x 8KB
    __shared__ __hip_bfloat16 smB[4][128 * 32];
    const int t = threadIdx.x;
    const int lane = t & 63, wid = t >> 6;
    const int wr = wid >> 1, wc = wid & 1;        // 2x2 waves, 64x64 each
    const int l15 = lane & 15, l4 = lane >> 4;

    // XCD-chunked bijective swizzle over row-major linear block id (m204)
    const int gx = gridDim.x;
    const int nwg = gx * gridDim.y;
    const int orig = blockIdx.y * gx + blockIdx.x;
    const int q8 = nwg >> 3, r8 = nwg & 7;
    const int xcd = orig & 7, linb = orig >> 3;
    const int swz = (xcd < r8 ? xcd * (q8 + 1) : r8 * (q8 + 1) + (xcd - r8) * q8) + linb;
    const int m0 = (swz / gx) << 7;
    const int n0 = (swz - (swz / gx) * gx) << 7;

    // fragment read byte offsets within one 8KB buffer (swizzled)
    int ra[4], rb[4];
    #pragma unroll
    for (int f = 0; f < 4; ++f) {
        int ml = wr * 64 + f * 16 + l15;
        ra[f] = ml * 64 + ((l4 ^ ((ml >> 1) & 3)) << 4);
        int nl = wc * 64 + f * 16 + l15;
        rb[f] = nl * 64 + ((l4 ^ ((nl >> 1) & 3)) << 4);
    }

    // staging source element offsets (inverse swizzle), 2 slots/thread each
    size_t aoff[2], boff[2];
    #pragma unroll
    for (int it = 0; it < 2; ++it) {
        int s = it * 256 + t;
        int m = s >> 2;
        int kc = (s & 3) ^ ((m >> 1) & 3);
        int gm = m0 + m; if (gm > M - 1) gm = M - 1;
        aoff[it] = (size_t)gm * K + kc * 8;
        boff[it] = (size_t)(n0 + m) * K + kc * 8;
    }
    const int wb = wid << 10;                      // wave-uniform LDS base
    const unsigned ldsA0 = (unsigned)(size_t)(lds_t*)&smA[0][0];
    const unsigned ldsB0 = (unsigned)(size_t)(lds_t*)&smB[0][0];

    auto STAGE = [&](int kt, int buf) {
        int k0e = kt << 5;
        gload16(A + aoff[0] + k0e, (char*)(&smA[buf][0]) + wb);
        gload16(A + aoff[1] + k0e, (char*)(&smA[buf][0]) + wb + 4096);
        gload16(BT + boff[0] + k0e, (char*)(&smB[buf][0]) + wb);
        gload16(BT + boff[1] + k0e, (char*)(&smB[buf][0]) + wb + 4096);
    };

    f32x4 acc[4][4];
    #pragma unroll
    for (int i = 0; i < 4; ++i)
        #pragma unroll
        for (int j = 0; j < 4; ++j) acc[i][j] = (f32x4){0.f, 0.f, 0.f, 0.f};

    const int nt = K >> 5;                         // >= 24 for all our GEMMs
    STAGE(0, 0); STAGE(1, 1); STAGE(2, 2);
    for (int kt = 0; kt < nt; ++kt) {
        const int rem = nt - 1 - kt;
        if (rem >= 2)      asm volatile("s_waitcnt vmcnt(8)" ::: "memory");
        else if (rem == 1) asm volatile("s_waitcnt vmcnt(4)" ::: "memory");
        else               asm volatile("s_waitcnt vmcnt(0)" ::: "memory");
        asm volatile("s_barrier" ::: "memory");
        const int cur = kt & 3;
        const unsigned sa = ldsA0 + (cur << 13);
        const unsigned sb = ldsB0 + (cur << 13);
        bf16x8 af[4], bf[4];
        #pragma unroll
        for (int f = 0; f < 4; ++f) {
            af[f] = ds_read128(sa + ra[f]);
            bf[f] = ds_read128(sb + rb[f]);
        }
        if (kt + 3 < nt) STAGE(kt + 3, (kt + 3) & 3);
        asm volatile("s_waitcnt lgkmcnt(0)" ::: "memory");
        __builtin_amdgcn_sched_barrier(0);
        #pragma unroll
        for (int i = 0; i < 4; ++i)
            #pragma unroll
            for (int j = 0; j < 4; ++j)
                acc[i][j] = __builtin_amdgcn_mfma_f32_16x16x32_bf16(af[i], bf[j], acc[i][j], 0, 0, 0);
    }

    // epilogue: bias / gelu / residual, fp32 math, templated store
    #pragma unroll
    for (int i = 0; i < 4; ++i) {
        int gmb = m0 + wr * 64 + i * 16 + l4 * 4;
        #pragma unroll
        for (int j = 0; j < 4; ++j) {
            int gn = n0 + wc * 64 + j * 16 + l15;
            float bv = bias ? bias[gn] : 0.f;
            #pragma unroll
            for (int r = 0; r < 4; ++r) {
                int gm = gmb + r;
                if (gm < M) {
                    float v = acc[i][j][r] + bv;
                    if (ACT) v = gelu_f(v);
                    if (RES) v += res[(size_t)gm * N + gn];
                    store_val(&C[(size_t)gm * N + gn], v);
                }
            }
        }
    }
}

// ---------------- fused flash attention (bf16 MFMA, 1 wave per block) ----------------
__global__ __launch_bounds__(64) void attn_fused(const __hip_bfloat16* __restrict__ qkv,
                                                 __hip_bfloat16* __restrict__ o) {
    __shared__ __hip_bfloat16 p_lds[32][40];
    __shared__ __hip_bfloat16 v_lds[32][68];
    const int qt = blockIdx.x, bh = blockIdx.y;
    const int b = bh / NHD, hd = bh - b * NHD;
    const int lane = threadIdx.x;
    const int l15 = lane & 15, l4 = lane >> 4;
    const size_t tb = (size_t)b * SS;
    const int hc = hd * 64;

    bf16x8 aq[2][2];
    #pragma unroll
    for (int qi = 0; qi < 2; ++qi) {
        int qr = qt * 32 + qi * 16 + l15;
        if (qr >= SS) qr = SS - 1;
        const __hip_bfloat16* qrow = qkv + (tb + qr) * 2304 + hc;
        #pragma unroll
        for (int kd = 0; kd < 2; ++kd)
            aq[qi][kd] = *(const bf16x8*)(qrow + kd * 32 + l4 * 8);
    }

    float m_run[2][4], l_run[2][4];
    f32x4 oa[2][4];
    #pragma unroll
    for (int qi = 0; qi < 2; ++qi)
        #pragma unroll
        for (int r = 0; r < 4; ++r) { m_run[qi][r] = -1e30f; l_run[qi][r] = 0.f; }
    #pragma unroll
    for (int qi = 0; qi < 2; ++qi)
        #pragma unroll
        for (int dt = 0; dt < 4; ++dt) oa[qi][dt] = (f32x4){0.f, 0.f, 0.f, 0.f};

    for (int kt = 0; kt < 10; ++kt) {
        const int kbase = kt * 32;
        bf16x4 vreg[8];
        #pragma unroll
        for (int it = 0; it < 8; ++it) {
            int vr = kbase + it * 4 + l4;
            if (vr >= SS) vr = SS - 1;
            vreg[it] = *(const bf16x4*)(qkv + (tb + vr) * 2304 + 1536 + hc + l15 * 4);
        }
        bf16x8 bk[2][2];
        #pragma unroll
        for (int ki = 0; ki < 2; ++ki) {
            int kr = kbase + ki * 16 + l15;
            if (kr >= SS) kr = SS - 1;
            const __hip_bfloat16* krow = qkv + (tb + kr) * 2304 + 768 + hc;
            #pragma unroll
            for (int kd = 0; kd < 2; ++kd)
                bk[ki][kd] = *(const bf16x8*)(krow + kd * 32 + l4 * 8);
        }
        f32x4 s[2][2];
        #pragma unroll
        for (int qi = 0; qi < 2; ++qi)
            #pragma unroll
            for (int ki = 0; ki < 2; ++ki) {
                f32x4 a = (f32x4){0.f, 0.f, 0.f, 0.f};
                #pragma unroll
                for (int kd = 0; kd < 2; ++kd)
                    a = __builtin_amdgcn_mfma_f32_16x16x32_bf16(aq[qi][kd], bk[ki][kd], a, 0, 0, 0);
                s[qi][ki] = a;
            }
        #pragma unroll
        for (int ki = 0; ki < 2; ++ki) {
            bool valid = (kbase + ki * 16 + l15) < SS;
            #pragma unroll
            for (int qi = 0; qi < 2; ++qi)
                #pragma unroll
                for (int r = 0; r < 4; ++r)
                    s[qi][ki][r] = valid ? s[qi][ki][r] * 0.125f : -1e30f;
        }
        float p[2][2][4];
        #pragma unroll
        for (int qi = 0; qi < 2; ++qi) {
            float tm[4];
            #pragma unroll
            for (int r = 0; r < 4; ++r) tm[r] = fmaxf(s[qi][0][r], s[qi][1][r]);
            #pragma unroll
            for (int sh = 1; sh < 16; sh <<= 1)
                #pragma unroll
                for (int r = 0; r < 4; ++r) tm[r] = fmaxf(tm[r], __shfl_xor(tm[r], sh));
            float rs[4];
            #pragma unroll
            for (int r = 0; r < 4; ++r) {
                float mn = fmaxf(m_run[qi][r], tm[r]);
                float corr = __expf(m_run[qi][r] - mn);
                m_run[qi][r] = mn;
                float p0 = __expf(s[qi][0][r] - mn);
                float p1 = __expf(s[qi][1][r] - mn);
                p[qi][0][r] = p0; p[qi][1][r] = p1;
                rs[r] = p0 + p1;
                l_run[qi][r] *= corr;
                #pragma unroll
                for (int dt = 0; dt < 4; ++dt) oa[qi][dt][r] *= corr;
            }
            #pragma unroll
            for (int sh = 1; sh < 16; sh <<= 1)
                #pragma unroll
                for (int r = 0; r < 4; ++r) rs[r] += __shfl_xor(rs[r], sh);
            #pragma unroll
            for (int r = 0; r < 4; ++r) l_run[qi][r] += rs[r];
        }
        #pragma unroll
        for (int qi = 0; qi < 2; ++qi)
            #pragma unroll
            for (int ki = 0; ki < 2; ++ki)
                #pragma unroll
                for (int r = 0; r < 4; ++r)
                    p_lds[qi * 16 + l4 * 4 + r][ki * 16 + l15] = __float2bfloat16(p[qi][ki][r]);
        #pragma unroll
        for (int it = 0; it < 8; ++it)
            *(bf16x4*)&v_lds[it * 4 + l4][l15 * 4] = vreg[it];
        __syncthreads();
        bf16x8 pa[2];
        #pragma unroll
        for (int qi = 0; qi < 2; ++qi)
            pa[qi] = *(const bf16x8*)&p_lds[qi * 16 + l15][l4 * 8];
        bf16x8 vb[4];
        #pragma unroll
        for (int dt = 0; dt < 4; ++dt) {
            bf16x8 v;
            #pragma unroll
            for (int j = 0; j < 8; ++j)
                v[j] = *(const short*)&v_lds[l4 * 8 + j][dt * 16 + l15];
            vb[dt] = v;
        }
        #pragma unroll
        for (int qi = 0; qi < 2; ++qi)
            #pragma unroll
            for (int dt = 0; dt < 4; ++dt)
                oa[qi][dt] = __builtin_amdgcn_mfma_f32_16x16x32_bf16(pa[qi], vb[dt], oa[qi][dt], 0, 0, 0);
        __syncthreads();
    }
    #pragma unroll
    for (int qi = 0; qi < 2; ++qi)
        #pragma unroll
        for (int r = 0; r < 4; ++r) {
            int q = qt * 32 + qi * 16 + l4 * 4 + r;
            if (q < SS) {
                float inv = 1.0f / l_run[qi][r];
                __hip_bfloat16* orow = o + (tb + q) * 768 + hc;
                #pragma unroll
                for (int dt = 0; dt < 4; ++dt)
                    orow[dt * 16 + l15] = __float2bfloat16(oa[qi][dt][r] * inv);
            }
        }
}

// ---------------- fp32 GEMM (head only: 16x1000x768) ----------------
__global__ __launch_bounds__(256) void gemm_f32(const float* __restrict__ A,
                                                const float* __restrict__ Bm,
                                                float* __restrict__ Cm,
                                                const float* __restrict__ bias,
                                                int M, int N, int Kd) {
    __shared__ float As[16][68];
    __shared__ float Bs[16][64];
    int tid = threadIdx.x;
    int m0 = blockIdx.y << 6;
    int n0 = blockIdx.x << 6;
    int tx = tid & 15, ty = tid >> 4;
    int arow = tid >> 2, acol = (tid & 3) << 2;
    int brow = tid >> 4, bcol = (tid & 15) << 2;
    float acc[4][4] = {};
    for (int k0 = 0; k0 < Kd; k0 += 16) {
        float4 av = make_float4(0.f, 0.f, 0.f, 0.f);
        int gm = m0 + arow;
        if (gm < M) av = *(const float4*)&A[(size_t)gm * Kd + k0 + acol];
        As[acol + 0][arow] = av.x;
        As[acol + 1][arow] = av.y;
        As[acol + 2][arow] = av.z;
        As[acol + 3][arow] = av.w;
        float4 bv = make_float4(0.f, 0.f, 0.f, 0.f);
        int gn = n0 + bcol;
        const float* brp = &Bm[(size_t)(k0 + brow) * N];
        if (gn + 3 < N) bv = *(const float4*)&brp[gn];
        else if (gn < N) {
            bv.x = brp[gn];
            if (gn + 1 < N) bv.y = brp[gn + 1];
            if (gn + 2 < N) bv.z = brp[gn + 2];
        }
        *(float4*)&Bs[brow][bcol] = bv;
        __syncthreads();
        #pragma unroll
        for (int kk = 0; kk < 16; ++kk) {
            float a[4], b[4];
            *(float4*)a = *(const float4*)&As[kk][ty << 2];
            *(float4*)b = *(const float4*)&Bs[kk][tx << 2];
            #pragma unroll
            for (int i = 0; i < 4; ++i)
                #pragma unroll
                for (int j = 0; j < 4; ++j)
                    acc[i][j] = fmaf(a[i], b[j], acc[i][j]);
        }
        __syncthreads();
    }
    #pragma unroll
    for (int i = 0; i < 4; ++i) {
        int gm = m0 + (ty << 2) + i;
        if (gm >= M) continue;
        #pragma unroll
        for (int j = 0; j < 4; ++j) {
            int gn = n0 + (tx << 2) + j;
            if (gn >= N) continue;
            Cm[(size_t)gm * N + gn] = acc[i][j] + (bias ? bias[gn] : 0.f);
        }
    }
}

// ---------------- workspace layout (float offsets) ----------------
static const size_t OFF_POOLED = 0;           //  9216 f
static const size_t OFF_IDX    = 10240;       //  4608 int
static const size_t OFF_H      = 16384;       //  3,551,232 f
static const size_t OFF_YB     = 3567616;     //  3,551,232 bf16 (1,775,616 f)
static const size_t OFF_OB     = 5343232;     //  3,551,232 bf16
static const size_t OFF_QKVB   = 7118848;     // 10,653,696 bf16 (5,326,848 f)
static const size_t OFF_WBUF   = 12445696;    //  7,077,888 bf16 (3,538,944 f)
static const size_t OFF_PWB    = 15984640;    //    589,824 bf16 (294,912 f)
static const size_t OFF_YF     = 16279552;    //     12,288 f
static const size_t OFF_BIG    = 16291840;    //  7,102,464 f (col+temp / hidden)
// total 23,394,304 floats = 93.6 MB

extern "C" void kernel_launch(void* const* d_in, const int* in_sizes, int n_in,
                              void* d_out, int out_size, void* d_ws, size_t ws_size,
                              hipStream_t stream) {
    const float* x       = (const float*)d_in[0];
    const float* patch_w = (const float*)d_in[1];
    const float* patch_b = (const float*)d_in[2];
    const float* cls_tok = (const float*)d_in[3];
    const float* pos_emb = (const float*)d_in[4];
    const float* ln1_g   = (const float*)d_in[5];
    const float* ln1_b   = (const float*)d_in[6];
    const float* Wqkv    = (const float*)d_in[7];
    const float* bqkv    = (const float*)d_in[8];
    const float* Wo      = (const float*)d_in[9];
    const float* bo      = (const float*)d_in[10];
    const float* ln2_g   = (const float*)d_in[11];
    const float* ln2_b   = (const float*)d_in[12];
    const float* W1      = (const float*)d_in[13];
    const float* b1      = (const float*)d_in[14];
    const float* W2      = (const float*)d_in[15];
    const float* b2      = (const float*)d_in[16];
    const float* lnf_g   = (const float*)d_in[17];
    const float* lnf_b   = (const float*)d_in[18];
    const float* fc_w    = (const float*)d_in[19];
    const float* fc_b    = (const float*)d_in[20];
    float* out = (float*)d_out;
    float* ws  = (float*)d_ws;

    float*          pooled = ws + OFF_POOLED;
    int*            idxsel = (int*)(ws + OFF_IDX);
    float*          h      = ws + OFF_H;
    __hip_bfloat16* yb     = (__hip_bfloat16*)(ws + OFF_YB);
    __hip_bfloat16* ob     = (__hip_bfloat16*)(ws + OFF_OB);
    __hip_bfloat16* qkvb   = (__hip_bfloat16*)(ws + OFF_QKVB);
    __hip_bfloat16* wbuf   = (__hip_bfloat16*)(ws + OFF_WBUF);
    __hip_bfloat16* pwb    = (__hip_bfloat16*)(ws + OFF_PWB);
    float*          yf     = ws + OFF_YF;
    float*          big    = ws + OFF_BIG;
    __hip_bfloat16* col    = (__hip_bfloat16*)big;             // 3,538,944 bf16
    float*          temp   = big + 1769472;                    // 3,538,944 f
    __hip_bfloat16* hidden = (__hip_bfloat16*)big;             // 14,204,928 bf16

    __hip_bfloat16* wqkvT = wbuf;                              // [2304][768]
    __hip_bfloat16* woT   = wbuf + 1769472;                    // [768][768]
    __hip_bfloat16* w1T   = wbuf + 2359296;                    // [3072][768]
    __hip_bfloat16* w2T   = wbuf + 4718592;                    // [768][3072]

    // ---- sparse selection + patch embedding ----
    pool_kernel<<<BB * NPATCH, 256, 0, stream>>>(x, pooled);
    topk_kernel<<<BB, 576, 0, stream>>>(pooled, idxsel);
    convert_bf16<<<(589824 + 255) / 256, 256, 0, stream>>>(patch_w, pwb, 589824);
    im2col_kernel<<<BB * KSEL, 256, 0, stream>>>(x, idxsel, col);
    gemm_bf16<float, 0, 0><<<dim3(6, 36), 256, 0, stream>>>(col, pwb, temp, patch_b,
                                                            nullptr, 4608, DD, DD);
    assemble_tokens<<<BB * SS, 256, 0, stream>>>(temp, cls_tok, pos_emb, idxsel, h);

    const int M = BB * SS;            // 4624
    const int MG = 37;                // ceil(4624/128)

    // ---- transformer layers ----
    for (int i = 0; i < NLAY; ++i) {
        convert_layer<<<6912, 256, 0, stream>>>(Wqkv + (size_t)i * DD * 3 * DD,
                                                Wo + (size_t)i * DD * DD,
                                                W1 + (size_t)i * DD * FFD,
                                                W2 + (size_t)i * FFD * DD,
                                                wqkvT, woT, w1T, w2T);

        ln_kernel<__hip_bfloat16><<<M, 256, 0, stream>>>(h, yb, ln1_g + i * DD, ln1_b + i * DD, DD);
        gemm_bf16<__hip_bfloat16, 0, 0><<<dim3(18, MG), 256, 0, stream>>>(
            yb, wqkvT, qkvb, bqkv + (size_t)i * 3 * DD, nullptr, M, 3 * DD, DD);
        attn_fused<<<dim3(10, BB * NHD), 64, 0, stream>>>(qkvb, ob);
        gemm_bf16<float, 0, 1><<<dim3(6, MG), 256, 0, stream>>>(
            ob, woT, h, bo + (size_t)i * DD, h, M, DD, DD);
        ln_kernel<__hip_bfloat16><<<M, 256, 0, stream>>>(h, yb, ln2_g + i * DD, ln2_b + i * DD, DD);
        gemm_bf16<__hip_bfloat16, 1, 0><<<dim3(24, MG), 256, 0, stream>>>(
            yb, w1T, hidden, b1 + (size_t)i * FFD, nullptr, M, FFD, DD);
        gemm_bf16<float, 0, 1><<<dim3(6, MG), 256, 0, stream>>>(
            hidden, w2T, h, b2 + (size_t)i * DD, h, M, DD, FFD);
    }

    // ---- final LN on cls token + fp32 classifier head ----
    ln_kernel<float><<<BB, 256, 0, stream>>>(h, yf, lnf_g, lnf_b, (size_t)SS * DD);
    gemm_f32<<<dim3(16, 1), 256, 0, stream>>>(yf, fc_w, out, fc_b, BB, 1000, DD);
}

// Round 5
// 2917.615 us; speedup vs baseline: 4.8889x; 1.0310x over previous
//
#include <hip/hip_runtime.h>
#include <hip/hip_bf16.h>
#include <math.h>

// ---------------- problem constants ----------------
#define BB 16
#define SS 289          // 1 cls + 288 selected tokens
#define DD 768
#define FFD 3072
#define NHD 12
#define NLAY 12
#define KSEL 288
#define NPATCH 576

typedef short bf16x8 __attribute__((ext_vector_type(8)));
typedef short bf16x4 __attribute__((ext_vector_type(4)));
typedef float f32x4 __attribute__((ext_vector_type(4)));

typedef __attribute__((address_space(3))) void lds_t;
typedef __attribute__((address_space(1))) const void glb_t;

__device__ __forceinline__ void gload16(const void* g, void* l) {
    __builtin_amdgcn_global_load_lds((glb_t*)g, (lds_t*)l, 16, 0, 0);
}

// inline-asm LDS read: invisible to compiler alias analysis, so no auto
// vmcnt(0) drain against outstanding global_load_lds (rule #18 discipline:
// caller must s_waitcnt lgkmcnt(0) + sched_barrier(0) before consuming).
__device__ __forceinline__ bf16x8 ds_read128(unsigned addr) {
    bf16x8 r;
    asm volatile("ds_read_b128 %0, %1" : "=v"(r) : "v"(addr));
    return r;
}

__device__ __forceinline__ float gelu_f(float v) {
    return 0.5f * v * (1.0f + erff(v * 0.70710678118654752f));
}

__device__ __forceinline__ void store_val(float* p, float v) { *p = v; }
__device__ __forceinline__ void store_val(__hip_bfloat16* p, float v) { *p = __float2bfloat16(v); }

// ---------------- patch pooling (channel 0, 16x16 mean) ----------------
__global__ __launch_bounds__(256) void pool_kernel(const float* __restrict__ x,
                                                   float* __restrict__ pooled) {
    int bp = blockIdx.x;
    int b = bp / NPATCH, p = bp - b * NPATCH;
    int gi = p / 24, gj = p - gi * 24;
    int tid = threadIdx.x;
    int pi = tid >> 4, pj = tid & 15;
    float v = x[((size_t)(b * 3) * 384 + gi * 16 + pi) * 384 + gj * 16 + pj];
    #pragma unroll
    for (int o = 32; o > 0; o >>= 1) v += __shfl_down(v, o);
    __shared__ float red[4];
    if ((tid & 63) == 0) red[tid >> 6] = v;
    __syncthreads();
    if (tid == 0) pooled[bp] = (red[0] + red[1] + red[2] + red[3]) * (1.0f / 256.0f);
}

// ---------------- exact stable top-k via rank counting ----------------
__global__ __launch_bounds__(576) void topk_kernel(const float* __restrict__ pooled,
                                                   int* __restrict__ idxsel) {
    __shared__ float a[NPATCH];
    int b = blockIdx.x, tid = threadIdx.x;
    a[tid] = fabsf(pooled[b * NPATCH + tid]);
    __syncthreads();
    float mine = a[tid];
    int rank = 0;
    for (int j = 0; j < NPATCH; ++j) {
        float aj = a[j];
        rank += (aj > mine) || (aj == mine && j < tid);
    }
    if (rank < KSEL) idxsel[b * KSEL + rank] = tid;
}

// ---------------- fp32 -> bf16 straight convert ----------------
__global__ __launch_bounds__(256) void convert_bf16(const float* __restrict__ in,
                                                    __hip_bfloat16* __restrict__ out,
                                                    int n) {
    int i = blockIdx.x * 256 + threadIdx.x;
    if (i < n) out[i] = __float2bfloat16(in[i]);
}

// ---------------- all 4 layer weights: fp32 [K][N] -> bf16 [N][K], one launch ----------------
__global__ __launch_bounds__(256) void convert_layer(const float* __restrict__ wqkv,
                                                     const float* __restrict__ wo,
                                                     const float* __restrict__ w1,
                                                     const float* __restrict__ w2,
                                                     __hip_bfloat16* __restrict__ oqkv,
                                                     __hip_bfloat16* __restrict__ owo,
                                                     __hip_bfloat16* __restrict__ ow1,
                                                     __hip_bfloat16* __restrict__ ow2) {
    __shared__ float tb[32][33];
    int bid = blockIdx.x;
    const float* W; __hip_bfloat16* O; int K, N, tile;
    if (bid < 1728)      { W = wqkv; O = oqkv; K = 768;  N = 2304; tile = bid; }
    else if (bid < 2304) { W = wo;   O = owo;  K = 768;  N = 768;  tile = bid - 1728; }
    else if (bid < 4608) { W = w1;   O = ow1;  K = 768;  N = 3072; tile = bid - 2304; }
    else                 { W = w2;   O = ow2;  K = 3072; N = 768;  tile = bid - 4608; }
    int ntx = N >> 5;
    int n0 = (tile % ntx) << 5, k0 = (tile / ntx) << 5;
    int t = threadIdx.x;
    int r = t >> 3, c = (t & 7) << 2;
    float4 v = *(const float4*)&W[(size_t)(k0 + r) * N + n0 + c];
    tb[r][c] = v.x; tb[r][c + 1] = v.y; tb[r][c + 2] = v.z; tb[r][c + 3] = v.w;
    __syncthreads();
    int n = t >> 3, k = (t & 7) << 2;
    __hip_bfloat16* dst = &O[(size_t)(n0 + n) * K + k0 + k];
    #pragma unroll
    for (int j = 0; j < 4; ++j) dst[j] = __float2bfloat16(tb[k + j][n]);
}

// ---------------- im2col of SELECTED patches only (bf16 out) ----------------
__global__ __launch_bounds__(256) void im2col_kernel(const float* __restrict__ x,
                                                     const int* __restrict__ idxsel,
                                                     __hip_bfloat16* __restrict__ col) {
    int t = blockIdx.x;
    int b = t / KSEL, r = t - b * KSEL;
    int p = idxsel[b * KSEL + r];
    int gi = p / 24, gj = p - gi * 24;
    int tid = threadIdx.x;
    int pi = tid >> 4, pj = tid & 15;
    __hip_bfloat16* crow = col + (size_t)t * 768;
    #pragma unroll
    for (int c = 0; c < 3; ++c)
        crow[c * 256 + tid] = __float2bfloat16(
            x[((size_t)(b * 3 + c) * 384 + gi * 16 + pi) * 384 + gj * 16 + pj]);
}

// ---------------- assemble h: cls + selected tokens + pos_emb (fp32) ----------------
__global__ __launch_bounds__(256) void assemble_tokens(const float* __restrict__ temp,
                                                       const float* __restrict__ cls_tok,
                                                       const float* __restrict__ pos_emb,
                                                       const int* __restrict__ idxsel,
                                                       float* __restrict__ h) {
    int row = blockIdx.x;
    int b = row / SS, s = row - b * SS;
    int tid = threadIdx.x;
    float* hrow = h + (size_t)row * DD;
    if (s == 0) {
        #pragma unroll
        for (int c = 0; c < 3; ++c) {
            int j = c * 256 + tid;
            hrow[j] = cls_tok[j] + pos_emb[j];
        }
    } else {
        int r = s - 1;
        int p = idxsel[b * KSEL + r];
        const float* trow = temp + (size_t)(b * KSEL + r) * DD;
        const float* pe = pos_emb + (size_t)(1 + p) * DD;
        #pragma unroll
        for (int c = 0; c < 3; ++c) {
            int j = c * 256 + tid;
            hrow[j] = trow[j] + pe[j];
        }
    }
}

// ---------------- LayerNorm over 768, templated output dtype ----------------
template <typename T>
__global__ __launch_bounds__(256) void ln_kernel(const float* __restrict__ in,
                                                 T* __restrict__ out,
                                                 const float* __restrict__ g,
                                                 const float* __restrict__ be,
                                                 size_t in_stride) {
    int row = blockIdx.x;
    const float* r = in + (size_t)row * in_stride;
    T* w = out + (size_t)row * DD;
    int tid = threadIdx.x;
    float v0 = r[tid], v1 = r[256 + tid], v2 = r[512 + tid];
    float s = v0 + v1 + v2;
    #pragma unroll
    for (int o = 32; o > 0; o >>= 1) s += __shfl_down(s, o);
    __shared__ float red[4];
    if ((tid & 63) == 0) red[tid >> 6] = s;
    __syncthreads();
    float mu = (red[0] + red[1] + red[2] + red[3]) * (1.0f / 768.0f);
    float d0 = v0 - mu, d1 = v1 - mu, d2 = v2 - mu;
    float q = d0 * d0 + d1 * d1 + d2 * d2;
    #pragma unroll
    for (int o = 32; o > 0; o >>= 1) q += __shfl_down(q, o);
    __syncthreads();
    if ((tid & 63) == 0) red[tid >> 6] = q;
    __syncthreads();
    float var = (red[0] + red[1] + red[2] + red[3]) * (1.0f / 768.0f);
    float rs = rsqrtf(var + 1e-6f);
    store_val(&w[tid],       d0 * rs * g[tid]       + be[tid]);
    store_val(&w[256 + tid], d1 * rs * g[256 + tid] + be[256 + tid]);
    store_val(&w[512 + tid], d2 * rs * g[512 + tid] + be[512 + tid]);
}

// ---------------- bf16 MFMA GEMM: C = A[M][K] @ BT[N][K]^T ----------------
// 128x128 tile, BK=32, 4 waves, global_load_lds w=16, LDS XOR swizzle (both sides).
// Depth-2 pipeline: 3 LDS buffers (48KB -> 3 blocks/CU), counted s_waitcnt vmcnt(4),
// raw s_barrier, inline-asm ds_read_b128, lgkmcnt(0)+sched_barrier(0) before MFMA.
// R5: traded depth-3/64KB (2 blocks/CU) for depth-2/48KB (3 blocks/CU) — inter-block
// overlap (m114) is worth more than the extra prefetch depth.
template <typename OUT_T, int ACT, int RES>
__global__ __launch_bounds__(256) void gemm_bf16(const __hip_bfloat16* __restrict__ A,
                                                 const __hip_bfloat16* __restrict__ BT,
                                                 OUT_T* __restrict__ C,
                                                 const float* __restrict__ bias,
                                                 const float* __restrict__ res,
                                                 int M, int N, int K) {
    __shared__ __hip_bfloat16 smA[3][128 * 32];   // 3 x 8KB
    __shared__ __hip_bfloat16 smB[3][128 * 32];
    const int t = threadIdx.x;
    const int lane = t & 63, wid = t >> 6;
    const int wr = wid >> 1, wc = wid & 1;        // 2x2 waves, 64x64 each
    const int l15 = lane & 15, l4 = lane >> 4;

    // XCD-chunked bijective swizzle over row-major linear block id (m204)
    const int gx = gridDim.x;
    const int nwg = gx * gridDim.y;
    const int orig = blockIdx.y * gx + blockIdx.x;
    const int q8 = nwg >> 3, r8 = nwg & 7;
    const int xcd = orig & 7, linb = orig >> 3;
    const int swz = (xcd < r8 ? xcd * (q8 + 1) : r8 * (q8 + 1) + (xcd - r8) * q8) + linb;
    const int m0 = (swz / gx) << 7;
    const int n0 = (swz - (swz / gx) * gx) << 7;

    // fragment read byte offsets within one 8KB buffer (swizzled)
    int ra[4], rb[4];
    #pragma unroll
    for (int f = 0; f < 4; ++f) {
        int ml = wr * 64 + f * 16 + l15;
        ra[f] = ml * 64 + ((l4 ^ ((ml >> 1) & 3)) << 4);
        int nl = wc * 64 + f * 16 + l15;
        rb[f] = nl * 64 + ((l4 ^ ((nl >> 1) & 3)) << 4);
    }

    // staging source element offsets (inverse swizzle), 2 slots/thread each
    size_t aoff[2], boff[2];
    #pragma unroll
    for (int it = 0; it < 2; ++it) {
        int s = it * 256 + t;
        int m = s >> 2;
        int kc = (s & 3) ^ ((m >> 1) & 3);
        int gm = m0 + m; if (gm > M - 1) gm = M - 1;
        aoff[it] = (size_t)gm * K + kc * 8;
        boff[it] = (size_t)(n0 + m) * K + kc * 8;
    }
    const int wb = wid << 10;                      // wave-uniform LDS base
    const unsigned ldsA0 = (unsigned)(size_t)(lds_t*)&smA[0][0];
    const unsigned ldsB0 = (unsigned)(size_t)(lds_t*)&smB[0][0];

    auto STAGE = [&](int kt, int buf) {
        int k0e = kt << 5;
        gload16(A + aoff[0] + k0e, (char*)(&smA[buf][0]) + wb);
        gload16(A + aoff[1] + k0e, (char*)(&smA[buf][0]) + wb + 4096);
        gload16(BT + boff[0] + k0e, (char*)(&smB[buf][0]) + wb);
        gload16(BT + boff[1] + k0e, (char*)(&smB[buf][0]) + wb + 4096);
    };

    f32x4 acc[4][4];
    #pragma unroll
    for (int i = 0; i < 4; ++i)
        #pragma unroll
        for (int j = 0; j < 4; ++j) acc[i][j] = (f32x4){0.f, 0.f, 0.f, 0.f};

    const int nt = K >> 5;                         // >= 24 for all our GEMMs
    STAGE(0, 0); STAGE(1, 1);
    int cur = 0, stb = 2;
    for (int kt = 0; kt < nt; ++kt) {
        if (kt + 1 < nt) asm volatile("s_waitcnt vmcnt(4)" ::: "memory");
        else             asm volatile("s_waitcnt vmcnt(0)" ::: "memory");
        asm volatile("s_barrier" ::: "memory");
        if (kt + 2 < nt) STAGE(kt + 2, stb);       // buf (kt+2)%3 == (kt-1)%3, readers drained
        const unsigned sa = ldsA0 + cur * 8192u;
        const unsigned sb = ldsB0 + cur * 8192u;
        bf16x8 af[4], bf[4];
        #pragma unroll
        for (int f = 0; f < 4; ++f) {
            af[f] = ds_read128(sa + ra[f]);
            bf[f] = ds_read128(sb + rb[f]);
        }
        asm volatile("s_waitcnt lgkmcnt(0)" ::: "memory");
        __builtin_amdgcn_sched_barrier(0);
        #pragma unroll
        for (int i = 0; i < 4; ++i)
            #pragma unroll
            for (int j = 0; j < 4; ++j)
                acc[i][j] = __builtin_amdgcn_mfma_f32_16x16x32_bf16(af[i], bf[j], acc[i][j], 0, 0, 0);
        cur = cur == 2 ? 0 : cur + 1;
        stb = stb == 2 ? 0 : stb + 1;
    }

    // epilogue: bias / gelu / residual, fp32 math, templated store
    #pragma unroll
    for (int i = 0; i < 4; ++i) {
        int gmb = m0 + wr * 64 + i * 16 + l4 * 4;
        #pragma unroll
        for (int j = 0; j < 4; ++j) {
            int gn = n0 + wc * 64 + j * 16 + l15;
            float bv = bias ? bias[gn] : 0.f;
            #pragma unroll
            for (int r = 0; r < 4; ++r) {
                int gm = gmb + r;
                if (gm < M) {
                    float v = acc[i][j][r] + bv;
                    if (ACT) v = gelu_f(v);
                    if (RES) v += res[(size_t)gm * N + gn];
                    store_val(&C[(size_t)gm * N + gn], v);
                }
            }
        }
    }
}

// ---------------- fused flash attention (bf16 MFMA, 1 wave per block) ----------------
__global__ __launch_bounds__(64) void attn_fused(const __hip_bfloat16* __restrict__ qkv,
                                                 __hip_bfloat16* __restrict__ o) {
    __shared__ __hip_bfloat16 p_lds[32][40];
    __shared__ __hip_bfloat16 v_lds[32][68];
    const int qt = blockIdx.x, bh = blockIdx.y;
    const int b = bh / NHD, hd = bh - b * NHD;
    const int lane = threadIdx.x;
    const int l15 = lane & 15, l4 = lane >> 4;
    const size_t tb = (size_t)b * SS;
    const int hc = hd * 64;

    bf16x8 aq[2][2];
    #pragma unroll
    for (int qi = 0; qi < 2; ++qi) {
        int qr = qt * 32 + qi * 16 + l15;
        if (qr >= SS) qr = SS - 1;
        const __hip_bfloat16* qrow = qkv + (tb + qr) * 2304 + hc;
        #pragma unroll
        for (int kd = 0; kd < 2; ++kd)
            aq[qi][kd] = *(const bf16x8*)(qrow + kd * 32 + l4 * 8);
    }

    float m_run[2][4], l_run[2][4];
    f32x4 oa[2][4];
    #pragma unroll
    for (int qi = 0; qi < 2; ++qi)
        #pragma unroll
        for (int r = 0; r < 4; ++r) { m_run[qi][r] = -1e30f; l_run[qi][r] = 0.f; }
    #pragma unroll
    for (int qi = 0; qi < 2; ++qi)
        #pragma unroll
        for (int dt = 0; dt < 4; ++dt) oa[qi][dt] = (f32x4){0.f, 0.f, 0.f, 0.f};

    for (int kt = 0; kt < 10; ++kt) {
        const int kbase = kt * 32;
        bf16x4 vreg[8];
        #pragma unroll
        for (int it = 0; it < 8; ++it) {
            int vr = kbase + it * 4 + l4;
            if (vr >= SS) vr = SS - 1;
            vreg[it] = *(const bf16x4*)(qkv + (tb + vr) * 2304 + 1536 + hc + l15 * 4);
        }
        bf16x8 bk[2][2];
        #pragma unroll
        for (int ki = 0; ki < 2; ++ki) {
            int kr = kbase + ki * 16 + l15;
            if (kr >= SS) kr = SS - 1;
            const __hip_bfloat16* krow = qkv + (tb + kr) * 2304 + 768 + hc;
            #pragma unroll
            for (int kd = 0; kd < 2; ++kd)
                bk[ki][kd] = *(const bf16x8*)(krow + kd * 32 + l4 * 8);
        }
        f32x4 s[2][2];
        #pragma unroll
        for (int qi = 0; qi < 2; ++qi)
            #pragma unroll
            for (int ki = 0; ki < 2; ++ki) {
                f32x4 a = (f32x4){0.f, 0.f, 0.f, 0.f};
                #pragma unroll
                for (int kd = 0; kd < 2; ++kd)
                    a = __builtin_amdgcn_mfma_f32_16x16x32_bf16(aq[qi][kd], bk[ki][kd], a, 0, 0, 0);
                s[qi][ki] = a;
            }
        #pragma unroll
        for (int ki = 0; ki < 2; ++ki) {
            bool valid = (kbase + ki * 16 + l15) < SS;
            #pragma unroll
            for (int qi = 0; qi < 2; ++qi)
                #pragma unroll
                for (int r = 0; r < 4; ++r)
                    s[qi][ki][r] = valid ? s[qi][ki][r] * 0.125f : -1e30f;
        }
        float p[2][2][4];
        #pragma unroll
        for (int qi = 0; qi < 2; ++qi) {
            float tm[4];
            #pragma unroll
            for (int r = 0; r < 4; ++r) tm[r] = fmaxf(s[qi][0][r], s[qi][1][r]);
            #pragma unroll
            for (int sh = 1; sh < 16; sh <<= 1)
                #pragma unroll
                for (int r = 0; r < 4; ++r) tm[r] = fmaxf(tm[r], __shfl_xor(tm[r], sh));
            float rs[4];
            #pragma unroll
            for (int r = 0; r < 4; ++r) {
                float mn = fmaxf(m_run[qi][r], tm[r]);
                float corr = __expf(m_run[qi][r] - mn);
                m_run[qi][r] = mn;
                float p0 = __expf(s[qi][0][r] - mn);
                float p1 = __expf(s[qi][1][r] - mn);
                p[qi][0][r] = p0; p[qi][1][r] = p1;
                rs[r] = p0 + p1;
                l_run[qi][r] *= corr;
                #pragma unroll
                for (int dt = 0; dt < 4; ++dt) oa[qi][dt][r] *= corr;
            }
            #pragma unroll
            for (int sh = 1; sh < 16; sh <<= 1)
                #pragma unroll
                for (int r = 0; r < 4; ++r) rs[r] += __shfl_xor(rs[r], sh);
            #pragma unroll
            for (int r = 0; r < 4; ++r) l_run[qi][r] += rs[r];
        }
        #pragma unroll
        for (int qi = 0; qi < 2; ++qi)
            #pragma unroll
            for (int ki = 0; ki < 2; ++ki)
                #pragma unroll
                for (int r = 0; r < 4; ++r)
                    p_lds[qi * 16 + l4 * 4 + r][ki * 16 + l15] = __float2bfloat16(p[qi][ki][r]);
        #pragma unroll
        for (int it = 0; it < 8; ++it)
            *(bf16x4*)&v_lds[it * 4 + l4][l15 * 4] = vreg[it];
        __syncthreads();
        bf16x8 pa[2];
        #pragma unroll
        for (int qi = 0; qi < 2; ++qi)
            pa[qi] = *(const bf16x8*)&p_lds[qi * 16 + l15][l4 * 8];
        bf16x8 vb[4];
        #pragma unroll
        for (int dt = 0; dt < 4; ++dt) {
            bf16x8 v;
            #pragma unroll
            for (int j = 0; j < 8; ++j)
                v[j] = *(const short*)&v_lds[l4 * 8 + j][dt * 16 + l15];
            vb[dt] = v;
        }
        #pragma unroll
        for (int qi = 0; qi < 2; ++qi)
            #pragma unroll
            for (int dt = 0; dt < 4; ++dt)
                oa[qi][dt] = __builtin_amdgcn_mfma_f32_16x16x32_bf16(pa[qi], vb[dt], oa[qi][dt], 0, 0, 0);
        __syncthreads();
    }
    #pragma unroll
    for (int qi = 0; qi < 2; ++qi)
        #pragma unroll
        for (int r = 0; r < 4; ++r) {
            int q = qt * 32 + qi * 16 + l4 * 4 + r;
            if (q < SS) {
                float inv = 1.0f / l_run[qi][r];
                __hip_bfloat16* orow = o + (tb + q) * 768 + hc;
                #pragma unroll
                for (int dt = 0; dt < 4; ++dt)
                    orow[dt * 16 + l15] = __float2bfloat16(oa[qi][dt][r] * inv);
            }
        }
}

// ---------------- fp32 GEMM (head only: 16x1000x768) ----------------
__global__ __launch_bounds__(256) void gemm_f32(const float* __restrict__ A,
                                                const float* __restrict__ Bm,
                                                float* __restrict__ Cm,
                                                const float* __restrict__ bias,
                                                int M, int N, int Kd) {
    __shared__ float As[16][68];
    __shared__ float Bs[16][64];
    int tid = threadIdx.x;
    int m0 = blockIdx.y << 6;
    int n0 = blockIdx.x << 6;
    int tx = tid & 15, ty = tid >> 4;
    int arow = tid >> 2, acol = (tid & 3) << 2;
    int brow = tid >> 4, bcol = (tid & 15) << 2;
    float acc[4][4] = {};
    for (int k0 = 0; k0 < Kd; k0 += 16) {
        float4 av = make_float4(0.f, 0.f, 0.f, 0.f);
        int gm = m0 + arow;
        if (gm < M) av = *(const float4*)&A[(size_t)gm * Kd + k0 + acol];
        As[acol + 0][arow] = av.x;
        As[acol + 1][arow] = av.y;
        As[acol + 2][arow] = av.z;
        As[acol + 3][arow] = av.w;
        float4 bv = make_float4(0.f, 0.f, 0.f, 0.f);
        int gn = n0 + bcol;
        const float* brp = &Bm[(size_t)(k0 + brow) * N];
        if (gn + 3 < N) bv = *(const float4*)&brp[gn];
        else if (gn < N) {
            bv.x = brp[gn];
            if (gn + 1 < N) bv.y = brp[gn + 1];
            if (gn + 2 < N) bv.z = brp[gn + 2];
        }
        *(float4*)&Bs[brow][bcol] = bv;
        __syncthreads();
        #pragma unroll
        for (int kk = 0; kk < 16; ++kk) {
            float a[4], b[4];
            *(float4*)a = *(const float4*)&As[kk][ty << 2];
            *(float4*)b = *(const float4*)&Bs[kk][tx << 2];
            #pragma unroll
            for (int i = 0; i < 4; ++i)
                #pragma unroll
                for (int j = 0; j < 4; ++j)
                    acc[i][j] = fmaf(a[i], b[j], acc[i][j]);
        }
        __syncthreads();
    }
    #pragma unroll
    for (int i = 0; i < 4; ++i) {
        int gm = m0 + (ty << 2) + i;
        if (gm >= M) continue;
        #pragma unroll
        for (int j = 0; j < 4; ++j) {
            int gn = n0 + (tx << 2) + j;
            if (gn >= N) continue;
            Cm[(size_t)gm * N + gn] = acc[i][j] + (bias ? bias[gn] : 0.f);
        }
    }
}

// ---------------- workspace layout (float offsets) ----------------
static const size_t OFF_POOLED = 0;           //  9216 f
static const size_t OFF_IDX    = 10240;       //  4608 int
static const size_t OFF_H      = 16384;       //  3,551,232 f
static const size_t OFF_YB     = 3567616;     //  3,551,232 bf16 (1,775,616 f)
static const size_t OFF_OB     = 5343232;     //  3,551,232 bf16
static const size_t OFF_QKVB   = 7118848;     // 10,653,696 bf16 (5,326,848 f)
static const size_t OFF_WBUF   = 12445696;    //  7,077,888 bf16 (3,538,944 f)
static const size_t OFF_PWB    = 15984640;    //    589,824 bf16 (294,912 f)
static const size_t OFF_YF     = 16279552;    //     12,288 f
static const size_t OFF_BIG    = 16291840;    //  7,102,464 f (col+temp / hidden)
// total 23,394,304 floats = 93.6 MB

extern "C" void kernel_launch(void* const* d_in, const int* in_sizes, int n_in,
                              void* d_out, int out_size, void* d_ws, size_t ws_size,
                              hipStream_t stream) {
    const float* x       = (const float*)d_in[0];
    const float* patch_w = (const float*)d_in[1];
    const float* patch_b = (const float*)d_in[2];
    const float* cls_tok = (const float*)d_in[3];
    const float* pos_emb = (const float*)d_in[4];
    const float* ln1_g   = (const float*)d_in[5];
    const float* ln1_b   = (const float*)d_in[6];
    const float* Wqkv    = (const float*)d_in[7];
    const float* bqkv    = (const float*)d_in[8];
    const float* Wo      = (const float*)d_in[9];
    const float* bo      = (const float*)d_in[10];
    const float* ln2_g   = (const float*)d_in[11];
    const float* ln2_b   = (const float*)d_in[12];
    const float* W1      = (const float*)d_in[13];
    const float* b1      = (const float*)d_in[14];
    const float* W2      = (const float*)d_in[15];
    const float* b2      = (const float*)d_in[16];
    const float* lnf_g   = (const float*)d_in[17];
    const float* lnf_b   = (const float*)d_in[18];
    const float* fc_w    = (const float*)d_in[19];
    const float* fc_b    = (const float*)d_in[20];
    float* out = (float*)d_out;
    float* ws  = (float*)d_ws;

    float*          pooled = ws + OFF_POOLED;
    int*            idxsel = (int*)(ws + OFF_IDX);
    float*          h      = ws + OFF_H;
    __hip_bfloat16* yb     = (__hip_bfloat16*)(ws + OFF_YB);
    __hip_bfloat16* ob     = (__hip_bfloat16*)(ws + OFF_OB);
    __hip_bfloat16* qkvb   = (__hip_bfloat16*)(ws + OFF_QKVB);
    __hip_bfloat16* wbuf   = (__hip_bfloat16*)(ws + OFF_WBUF);
    __hip_bfloat16* pwb    = (__hip_bfloat16*)(ws + OFF_PWB);
    float*          yf     = ws + OFF_YF;
    float*          big    = ws + OFF_BIG;
    __hip_bfloat16* col    = (__hip_bfloat16*)big;             // 3,538,944 bf16
    float*          temp   = big + 1769472;                    // 3,538,944 f
    __hip_bfloat16* hidden = (__hip_bfloat16*)big;             // 14,204,928 bf16

    __hip_bfloat16* wqkvT = wbuf;                              // [2304][768]
    __hip_bfloat16* woT   = wbuf + 1769472;                    // [768][768]
    __hip_bfloat16* w1T   = wbuf + 2359296;                    // [3072][768]
    __hip_bfloat16* w2T   = wbuf + 4718592;                    // [768][3072]

    // ---- sparse selection + patch embedding ----
    pool_kernel<<<BB * NPATCH, 256, 0, stream>>>(x, pooled);
    topk_kernel<<<BB, 576, 0, stream>>>(pooled, idxsel);
    convert_bf16<<<(589824 + 255) / 256, 256, 0, stream>>>(patch_w, pwb, 589824);
    im2col_kernel<<<BB * KSEL, 256, 0, stream>>>(x, idxsel, col);
    gemm_bf16<float, 0, 0><<<dim3(6, 36), 256, 0, stream>>>(col, pwb, temp, patch_b,
                                                            nullptr, 4608, DD, DD);
    assemble_tokens<<<BB * SS, 256, 0, stream>>>(temp, cls_tok, pos_emb, idxsel, h);

    const int M = BB * SS;            // 4624
    const int MG = 37;                // ceil(4624/128)

    // ---- transformer layers ----
    for (int i = 0; i < NLAY; ++i) {
        convert_layer<<<6912, 256, 0, stream>>>(Wqkv + (size_t)i * DD * 3 * DD,
                                                Wo + (size_t)i * DD * DD,
                                                W1 + (size_t)i * DD * FFD,
                                                W2 + (size_t)i * FFD * DD,
                                                wqkvT, woT, w1T, w2T);

        ln_kernel<__hip_bfloat16><<<M, 256, 0, stream>>>(h, yb, ln1_g + i * DD, ln1_b + i * DD, DD);
        gemm_bf16<__hip_bfloat16, 0, 0><<<dim3(18, MG), 256, 0, stream>>>(
            yb, wqkvT, qkvb, bqkv + (size_t)i * 3 * DD, nullptr, M, 3 * DD, DD);
        attn_fused<<<dim3(10, BB * NHD), 64, 0, stream>>>(qkvb, ob);
        gemm_bf16<float, 0, 1><<<dim3(6, MG), 256, 0, stream>>>(
            ob, woT, h, bo + (size_t)i * DD, h, M, DD, DD);
        ln_kernel<__hip_bfloat16><<<M, 256, 0, stream>>>(h, yb, ln2_g + i * DD, ln2_b + i * DD, DD);
        gemm_bf16<__hip_bfloat16, 1, 0><<<dim3(24, MG), 256, 0, stream>>>(
            yb, w1T, hidden, b1 + (size_t)i * FFD, nullptr, M, FFD, DD);
        gemm_bf16<float, 0, 1><<<dim3(6, MG), 256, 0, stream>>>(
            hidden, w2T, h, b2 + (size_t)i * DD, h, M, DD, FFD);
    }

    // ---- final LN on cls token + fp32 classifier head ----
    ln_kernel<float><<<BB, 256, 0, stream>>>(h, yf, lnf_g, lnf_b, (size_t)SS * DD);
    gemm_f32<<<dim3(16, 1), 256, 0, stream>>>(yf, fc_w, out, fc_b, BB, 1000, DD);
}

// Round 6
// 2463.859 us; speedup vs baseline: 5.7892x; 1.1842x over previous
//
#include <hip/hip_runtime.h>
#include <hip/hip_bf16.h>
#include <math.h>

// ---------------- problem constants ----------------
#define BB 16
#define SS 289          // 1 cls + 288 selected tokens
#define DD 768
#define FFD 3072
#define NHD 12
#define NLAY 12
#define KSEL 288
#define NPATCH 576

typedef short bf16x8 __attribute__((ext_vector_type(8)));
typedef short bf16x4 __attribute__((ext_vector_type(4)));
typedef float f32x4 __attribute__((ext_vector_type(4)));

typedef __attribute__((address_space(3))) void lds_t;
typedef __attribute__((address_space(1))) const void glb_t;

__device__ __forceinline__ void gload16(const void* g, void* l) {
    __builtin_amdgcn_global_load_lds((glb_t*)g, (lds_t*)l, 16, 0, 0);
}

// inline-asm LDS read: invisible to compiler alias analysis, so no auto
// vmcnt(0) drain against outstanding global_load_lds (rule #18 discipline:
// caller must s_waitcnt lgkmcnt(0) + sched_barrier(0) before consuming).
__device__ __forceinline__ bf16x8 ds_read128(unsigned addr) {
    bf16x8 r;
    asm volatile("ds_read_b128 %0, %1" : "=v"(r) : "v"(addr));
    return r;
}

__device__ __forceinline__ float gelu_f(float v) {
    return 0.5f * v * (1.0f + erff(v * 0.70710678118654752f));
}

__device__ __forceinline__ void store_val(float* p, float v) { *p = v; }
__device__ __forceinline__ void store_val(__hip_bfloat16* p, float v) { *p = __float2bfloat16(v); }

// ---------------- patch pooling (channel 0, 16x16 mean) ----------------
__global__ __launch_bounds__(256) void pool_kernel(const float* __restrict__ x,
                                                   float* __restrict__ pooled) {
    int bp = blockIdx.x;
    int b = bp / NPATCH, p = bp - b * NPATCH;
    int gi = p / 24, gj = p - gi * 24;
    int tid = threadIdx.x;
    int pi = tid >> 4, pj = tid & 15;
    float v = x[((size_t)(b * 3) * 384 + gi * 16 + pi) * 384 + gj * 16 + pj];
    #pragma unroll
    for (int o = 32; o > 0; o >>= 1) v += __shfl_down(v, o);
    __shared__ float red[4];
    if ((tid & 63) == 0) red[tid >> 6] = v;
    __syncthreads();
    if (tid == 0) pooled[bp] = (red[0] + red[1] + red[2] + red[3]) * (1.0f / 256.0f);
}

// ---------------- exact stable top-k via rank counting ----------------
__global__ __launch_bounds__(576) void topk_kernel(const float* __restrict__ pooled,
                                                   int* __restrict__ idxsel) {
    __shared__ float a[NPATCH];
    int b = blockIdx.x, tid = threadIdx.x;
    a[tid] = fabsf(pooled[b * NPATCH + tid]);
    __syncthreads();
    float mine = a[tid];
    int rank = 0;
    for (int j = 0; j < NPATCH; ++j) {
        float aj = a[j];
        rank += (aj > mine) || (aj == mine && j < tid);
    }
    if (rank < KSEL) idxsel[b * KSEL + rank] = tid;
}

// ---------------- fp32 -> bf16 straight convert ----------------
__global__ __launch_bounds__(256) void convert_bf16(const float* __restrict__ in,
                                                    __hip_bfloat16* __restrict__ out,
                                                    int n) {
    int i = blockIdx.x * 256 + threadIdx.x;
    if (i < n) out[i] = __float2bfloat16(in[i]);
}

// ---------------- all 4 layer weights: fp32 [K][N] -> bf16 [N][K], one launch ----------------
__global__ __launch_bounds__(256) void convert_layer(const float* __restrict__ wqkv,
                                                     const float* __restrict__ wo,
                                                     const float* __restrict__ w1,
                                                     const float* __restrict__ w2,
                                                     __hip_bfloat16* __restrict__ oqkv,
                                                     __hip_bfloat16* __restrict__ owo,
                                                     __hip_bfloat16* __restrict__ ow1,
                                                     __hip_bfloat16* __restrict__ ow2) {
    __shared__ float tb[32][33];
    int bid = blockIdx.x;
    const float* W; __hip_bfloat16* O; int K, N, tile;
    if (bid < 1728)      { W = wqkv; O = oqkv; K = 768;  N = 2304; tile = bid; }
    else if (bid < 2304) { W = wo;   O = owo;  K = 768;  N = 768;  tile = bid - 1728; }
    else if (bid < 4608) { W = w1;   O = ow1;  K = 768;  N = 3072; tile = bid - 2304; }
    else                 { W = w2;   O = ow2;  K = 3072; N = 768;  tile = bid - 4608; }
    int ntx = N >> 5;
    int n0 = (tile % ntx) << 5, k0 = (tile / ntx) << 5;
    int t = threadIdx.x;
    int r = t >> 3, c = (t & 7) << 2;
    float4 v = *(const float4*)&W[(size_t)(k0 + r) * N + n0 + c];
    tb[r][c] = v.x; tb[r][c + 1] = v.y; tb[r][c + 2] = v.z; tb[r][c + 3] = v.w;
    __syncthreads();
    int n = t >> 3, k = (t & 7) << 2;
    __hip_bfloat16* dst = &O[(size_t)(n0 + n) * K + k0 + k];
    #pragma unroll
    for (int j = 0; j < 4; ++j) dst[j] = __float2bfloat16(tb[k + j][n]);
}

// ---------------- im2col of SELECTED patches only (bf16 out) ----------------
__global__ __launch_bounds__(256) void im2col_kernel(const float* __restrict__ x,
                                                     const int* __restrict__ idxsel,
                                                     __hip_bfloat16* __restrict__ col) {
    int t = blockIdx.x;
    int b = t / KSEL, r = t - b * KSEL;
    int p = idxsel[b * KSEL + r];
    int gi = p / 24, gj = p - gi * 24;
    int tid = threadIdx.x;
    int pi = tid >> 4, pj = tid & 15;
    __hip_bfloat16* crow = col + (size_t)t * 768;
    #pragma unroll
    for (int c = 0; c < 3; ++c)
        crow[c * 256 + tid] = __float2bfloat16(
            x[((size_t)(b * 3 + c) * 384 + gi * 16 + pi) * 384 + gj * 16 + pj]);
}

// ---------------- assemble h: cls + selected tokens + pos_emb (fp32) ----------------
__global__ __launch_bounds__(256) void assemble_tokens(const float* __restrict__ temp,
                                                       const float* __restrict__ cls_tok,
                                                       const float* __restrict__ pos_emb,
                                                       const int* __restrict__ idxsel,
                                                       float* __restrict__ h) {
    int row = blockIdx.x;
    int b = row / SS, s = row - b * SS;
    int tid = threadIdx.x;
    float* hrow = h + (size_t)row * DD;
    if (s == 0) {
        #pragma unroll
        for (int c = 0; c < 3; ++c) {
            int j = c * 256 + tid;
            hrow[j] = cls_tok[j] + pos_emb[j];
        }
    } else {
        int r = s - 1;
        int p = idxsel[b * KSEL + r];
        const float* trow = temp + (size_t)(b * KSEL + r) * DD;
        const float* pe = pos_emb + (size_t)(1 + p) * DD;
        #pragma unroll
        for (int c = 0; c < 3; ++c) {
            int j = c * 256 + tid;
            hrow[j] = trow[j] + pe[j];
        }
    }
}

// ---------------- LayerNorm over 768, templated output dtype ----------------
template <typename T>
__global__ __launch_bounds__(256) void ln_kernel(const float* __restrict__ in,
                                                 T* __restrict__ out,
                                                 const float* __restrict__ g,
                                                 const float* __restrict__ be,
                                                 size_t in_stride) {
    int row = blockIdx.x;
    const float* r = in + (size_t)row * in_stride;
    T* w = out + (size_t)row * DD;
    int tid = threadIdx.x;
    float v0 = r[tid], v1 = r[256 + tid], v2 = r[512 + tid];
    float s = v0 + v1 + v2;
    #pragma unroll
    for (int o = 32; o > 0; o >>= 1) s += __shfl_down(s, o);
    __shared__ float red[4];
    if ((tid & 63) == 0) red[tid >> 6] = s;
    __syncthreads();
    float mu = (red[0] + red[1] + red[2] + red[3]) * (1.0f / 768.0f);
    float d0 = v0 - mu, d1 = v1 - mu, d2 = v2 - mu;
    float q = d0 * d0 + d1 * d1 + d2 * d2;
    #pragma unroll
    for (int o = 32; o > 0; o >>= 1) q += __shfl_down(q, o);
    __syncthreads();
    if ((tid & 63) == 0) red[tid >> 6] = q;
    __syncthreads();
    float var = (red[0] + red[1] + red[2] + red[3]) * (1.0f / 768.0f);
    float rs = rsqrtf(var + 1e-6f);
    store_val(&w[tid],       d0 * rs * g[tid]       + be[tid]);
    store_val(&w[256 + tid], d1 * rs * g[256 + tid] + be[256 + tid]);
    store_val(&w[512 + tid], d2 * rs * g[512 + tid] + be[512 + tid]);
}

// ---------------- bf16 MFMA GEMM: C = A[M][K] @ BT[N][K]^T ----------------
// R6: 128x256 tile, 8 waves (512 thr, 2x4 wave grid, each wave 64x64 out),
// BK=32, global_load_lds w=16, XOR swizzle both sides, 3 LDS buffers (72KB,
// 2 blocks/CU), depth-2 counted vmcnt(3), raw s_barrier, asm ds_read_b128.
// Rationale (R5 post-mortem): wall scales with block-steps/CU (resident blocks
// don't overlap the per-step chain) -> fatter blocks halve block-steps.
// SPLITK>1: blockIdx.z picks a K-chunk, raw partial written to part[z][M][N].
template <typename OUT_T, int ACT, int RES, int SPLITK>
__global__ __launch_bounds__(512) void gemm_bf16(const __hip_bfloat16* __restrict__ A,
                                                 const __hip_bfloat16* __restrict__ BT,
                                                 OUT_T* __restrict__ C,
                                                 const float* __restrict__ bias,
                                                 const float* __restrict__ res,
                                                 float* __restrict__ part,
                                                 int M, int N, int K) {
    __shared__ __hip_bfloat16 smA[3][128 * 32];   // 3 x 8KB
    __shared__ __hip_bfloat16 smB[3][256 * 32];   // 3 x 16KB
    const int t = threadIdx.x;
    const int lane = t & 63, wid = t >> 6;
    const int wr = wid >> 2, wc = wid & 3;        // 2x4 waves, 64x64 each
    const int l15 = lane & 15, l4 = lane >> 4;

    // XCD-chunked bijective swizzle over row-major linear block id (m204)
    const int gx = gridDim.x;
    const int nwg = gx * gridDim.y;
    const int orig = blockIdx.y * gx + blockIdx.x;
    const int q8 = nwg >> 3, r8 = nwg & 7;
    const int xcd = orig & 7, linb = orig >> 3;
    const int swz = (xcd < r8 ? xcd * (q8 + 1) : r8 * (q8 + 1) + (xcd - r8) * q8) + linb;
    const int m0 = (swz / gx) << 7;               // BM=128
    const int n0 = (swz - (swz / gx) * gx) << 8;  // BN=256

    const int Ksub = K / SPLITK;
    const int kz0 = blockIdx.z * Ksub;

    // fragment read byte offsets within one buffer (swizzled; row stride 64B)
    int ra[4], rb[4];
    #pragma unroll
    for (int f = 0; f < 4; ++f) {
        int ml = wr * 64 + f * 16 + l15;
        ra[f] = ml * 64 + ((l4 ^ ((ml >> 1) & 3)) << 4);
        int nl = wc * 64 + f * 16 + l15;
        rb[f] = nl * 64 + ((l4 ^ ((nl >> 1) & 3)) << 4);
    }

    // staging source offsets (inverse swizzle). A: 1 slot/thread; B: 2 slots.
    size_t aoff, boff[2];
    {
        int mA = t >> 2;
        int kcA = (t & 3) ^ ((mA >> 1) & 3);
        int gmA = m0 + mA; if (gmA > M - 1) gmA = M - 1;
        aoff = (size_t)gmA * K + kz0 + kcA * 8;
        #pragma unroll
        for (int it = 0; it < 2; ++it) {
            int s = it * 512 + t;
            int mB = s >> 2;
            int kc = (s & 3) ^ ((mB >> 1) & 3);
            boff[it] = (size_t)(n0 + mB) * K + kz0 + kc * 8;
        }
    }
    const int wb = wid << 10;                      // wave-uniform LDS base (1KB/wave)
    const unsigned ldsA0 = (unsigned)(size_t)(lds_t*)&smA[0][0];
    const unsigned ldsB0 = (unsigned)(size_t)(lds_t*)&smB[0][0];

    auto STAGE = [&](int kt, int buf) {
        int k0e = kt << 5;
        gload16(A + aoff + k0e,     (char*)(&smA[buf][0]) + wb);
        gload16(BT + boff[0] + k0e, (char*)(&smB[buf][0]) + wb);
        gload16(BT + boff[1] + k0e, (char*)(&smB[buf][0]) + 8192 + wb);
    };

    f32x4 acc[4][4];
    #pragma unroll
    for (int i = 0; i < 4; ++i)
        #pragma unroll
        for (int j = 0; j < 4; ++j) acc[i][j] = (f32x4){0.f, 0.f, 0.f, 0.f};

    const int nt = Ksub >> 5;                      // >= 12 for all our GEMMs
    STAGE(0, 0); STAGE(1, 1);
    int cur = 0, stb = 2;
    for (int kt = 0; kt < nt; ++kt) {
        if (kt + 1 < nt) asm volatile("s_waitcnt vmcnt(3)" ::: "memory");
        else             asm volatile("s_waitcnt vmcnt(0)" ::: "memory");
        asm volatile("s_barrier" ::: "memory");
        if (kt + 2 < nt) STAGE(kt + 2, stb);       // buf (kt+2)%3 == (kt-1)%3, readers drained
        const unsigned sa = ldsA0 + cur * 8192u;
        const unsigned sb = ldsB0 + cur * 16384u;
        bf16x8 af[4], bf[4];
        #pragma unroll
        for (int f = 0; f < 4; ++f) {
            af[f] = ds_read128(sa + ra[f]);
            bf[f] = ds_read128(sb + rb[f]);
        }
        asm volatile("s_waitcnt lgkmcnt(0)" ::: "memory");
        __builtin_amdgcn_sched_barrier(0);
        #pragma unroll
        for (int i = 0; i < 4; ++i)
            #pragma unroll
            for (int j = 0; j < 4; ++j)
                acc[i][j] = __builtin_amdgcn_mfma_f32_16x16x32_bf16(af[i], bf[j], acc[i][j], 0, 0, 0);
        cur = cur == 2 ? 0 : cur + 1;
        stb = stb == 2 ? 0 : stb + 1;
    }

    // epilogue
    if (SPLITK == 1) {
        #pragma unroll
        for (int i = 0; i < 4; ++i) {
            int gmb = m0 + wr * 64 + i * 16 + l4 * 4;
            #pragma unroll
            for (int j = 0; j < 4; ++j) {
                int gn = n0 + wc * 64 + j * 16 + l15;
                float bv = bias ? bias[gn] : 0.f;
                #pragma unroll
                for (int r = 0; r < 4; ++r) {
                    int gm = gmb + r;
                    if (gm < M) {
                        float v = acc[i][j][r] + bv;
                        if (ACT) v = gelu_f(v);
                        if (RES) v += res[(size_t)gm * N + gn];
                        store_val(&C[(size_t)gm * N + gn], v);
                    }
                }
            }
        }
    } else {
        float* pz = part + (size_t)blockIdx.z * M * N;
        #pragma unroll
        for (int i = 0; i < 4; ++i) {
            int gmb = m0 + wr * 64 + i * 16 + l4 * 4;
            #pragma unroll
            for (int j = 0; j < 4; ++j) {
                int gn = n0 + wc * 64 + j * 16 + l15;
                #pragma unroll
                for (int r = 0; r < 4; ++r) {
                    int gm = gmb + r;
                    if (gm < M) pz[(size_t)gm * N + gn] = acc[i][j][r];
                }
            }
        }
    }
}

// ---------------- split-K combine: h += sum_z part[z] + bias (float4) ----------------
template <int NPART>
__global__ __launch_bounds__(256) void combine_res(const float* __restrict__ part,
                                                   const float* __restrict__ bias,
                                                   float* __restrict__ h,
                                                   int MN, int N) {
    int i = (blockIdx.x * 256 + threadIdx.x) * 4;
    if (i >= MN) return;
    float4 v = *(const float4*)&part[i];
    #pragma unroll
    for (int z = 1; z < NPART; ++z) {
        float4 p = *(const float4*)&part[(size_t)z * MN + i];
        v.x += p.x; v.y += p.y; v.z += p.z; v.w += p.w;
    }
    int n = i % N;
    float4 bv = *(const float4*)&bias[n];
    float4 hv = *(const float4*)&h[i];
    v.x += bv.x + hv.x; v.y += bv.y + hv.y; v.z += bv.z + hv.z; v.w += bv.w + hv.w;
    *(float4*)&h[i] = v;
}

// ---------------- classifier head: out[16][1000] = yf[16][768] @ fc_w + fc_b ----------------
// grid (4,4): x -> 256-wide n-range, y -> 4-row m-group. LDS-broadcast yf rows.
__global__ __launch_bounds__(256) void head_gemm(const float* __restrict__ yf,
                                                 const float* __restrict__ fc_w,
                                                 const float* __restrict__ fc_b,
                                                 float* __restrict__ out) {
    __shared__ float ylds[4 * 768];
    const int tid = threadIdx.x;
    const int mh = blockIdx.y * 4;
    for (int i = tid; i < 4 * 768; i += 256) ylds[i] = yf[(size_t)(mh + (i >> 9) * 0 + i / 768) * 768 + i % 768];
    __syncthreads();
    const int n = blockIdx.x * 256 + tid;
    if (n >= 1000) return;
    float acc0 = 0.f, acc1 = 0.f, acc2 = 0.f, acc3 = 0.f;
    for (int k = 0; k < 768; ++k) {
        float w = fc_w[(size_t)k * 1000 + n];
        acc0 = fmaf(ylds[k], w, acc0);
        acc1 = fmaf(ylds[768 + k], w, acc1);
        acc2 = fmaf(ylds[1536 + k], w, acc2);
        acc3 = fmaf(ylds[2304 + k], w, acc3);
    }
    float b = fc_b[n];
    out[(size_t)(mh + 0) * 1000 + n] = acc0 + b;
    out[(size_t)(mh + 1) * 1000 + n] = acc1 + b;
    out[(size_t)(mh + 2) * 1000 + n] = acc2 + b;
    out[(size_t)(mh + 3) * 1000 + n] = acc3 + b;
}

// ---------------- fused flash attention (bf16 MFMA, 1 wave per block) ----------------
__global__ __launch_bounds__(64) void attn_fused(const __hip_bfloat16* __restrict__ qkv,
                                                 __hip_bfloat16* __restrict__ o) {
    __shared__ __hip_bfloat16 p_lds[32][40];
    __shared__ __hip_bfloat16 v_lds[32][68];
    const int qt = blockIdx.x, bh = blockIdx.y;
    const int b = bh / NHD, hd = bh - b * NHD;
    const int lane = threadIdx.x;
    const int l15 = lane & 15, l4 = lane >> 4;
    const size_t tb = (size_t)b * SS;
    const int hc = hd * 64;

    bf16x8 aq[2][2];
    #pragma unroll
    for (int qi = 0; qi < 2; ++qi) {
        int qr = qt * 32 + qi * 16 + l15;
        if (qr >= SS) qr = SS - 1;
        const __hip_bfloat16* qrow = qkv + (tb + qr) * 2304 + hc;
        #pragma unroll
        for (int kd = 0; kd < 2; ++kd)
            aq[qi][kd] = *(const bf16x8*)(qrow + kd * 32 + l4 * 8);
    }

    float m_run[2][4], l_run[2][4];
    f32x4 oa[2][4];
    #pragma unroll
    for (int qi = 0; qi < 2; ++qi)
        #pragma unroll
        for (int r = 0; r < 4; ++r) { m_run[qi][r] = -1e30f; l_run[qi][r] = 0.f; }
    #pragma unroll
    for (int qi = 0; qi < 2; ++qi)
        #pragma unroll
        for (int dt = 0; dt < 4; ++dt) oa[qi][dt] = (f32x4){0.f, 0.f, 0.f, 0.f};

    for (int kt = 0; kt < 10; ++kt) {
        const int kbase = kt * 32;
        bf16x4 vreg[8];
        #pragma unroll
        for (int it = 0; it < 8; ++it) {
            int vr = kbase + it * 4 + l4;
            if (vr >= SS) vr = SS - 1;
            vreg[it] = *(const bf16x4*)(qkv + (tb + vr) * 2304 + 1536 + hc + l15 * 4);
        }
        bf16x8 bk[2][2];
        #pragma unroll
        for (int ki = 0; ki < 2; ++ki) {
            int kr = kbase + ki * 16 + l15;
            if (kr >= SS) kr = SS - 1;
            const __hip_bfloat16* krow = qkv + (tb + kr) * 2304 + 768 + hc;
            #pragma unroll
            for (int kd = 0; kd < 2; ++kd)
                bk[ki][kd] = *(const bf16x8*)(krow + kd * 32 + l4 * 8);
        }
        f32x4 s[2][2];
        #pragma unroll
        for (int qi = 0; qi < 2; ++qi)
            #pragma unroll
            for (int ki = 0; ki < 2; ++ki) {
                f32x4 a = (f32x4){0.f, 0.f, 0.f, 0.f};
                #pragma unroll
                for (int kd = 0; kd < 2; ++kd)
                    a = __builtin_amdgcn_mfma_f32_16x16x32_bf16(aq[qi][kd], bk[ki][kd], a, 0, 0, 0);
                s[qi][ki] = a;
            }
        #pragma unroll
        for (int ki = 0; ki < 2; ++ki) {
            bool valid = (kbase + ki * 16 + l15) < SS;
            #pragma unroll
            for (int qi = 0; qi < 2; ++qi)
                #pragma unroll
                for (int r = 0; r < 4; ++r)
                    s[qi][ki][r] = valid ? s[qi][ki][r] * 0.125f : -1e30f;
        }
        float p[2][2][4];
        #pragma unroll
        for (int qi = 0; qi < 2; ++qi) {
            float tm[4];
            #pragma unroll
            for (int r = 0; r < 4; ++r) tm[r] = fmaxf(s[qi][0][r], s[qi][1][r]);
            #pragma unroll
            for (int sh = 1; sh < 16; sh <<= 1)
                #pragma unroll
                for (int r = 0; r < 4; ++r) tm[r] = fmaxf(tm[r], __shfl_xor(tm[r], sh));
            float rs[4];
            #pragma unroll
            for (int r = 0; r < 4; ++r) {
                float mn = fmaxf(m_run[qi][r], tm[r]);
                float corr = __expf(m_run[qi][r] - mn);
                m_run[qi][r] = mn;
                float p0 = __expf(s[qi][0][r] - mn);
                float p1 = __expf(s[qi][1][r] - mn);
                p[qi][0][r] = p0; p[qi][1][r] = p1;
                rs[r] = p0 + p1;
                l_run[qi][r] *= corr;
                #pragma unroll
                for (int dt = 0; dt < 4; ++dt) oa[qi][dt][r] *= corr;
            }
            #pragma unroll
            for (int sh = 1; sh < 16; sh <<= 1)
                #pragma unroll
                for (int r = 0; r < 4; ++r) rs[r] += __shfl_xor(rs[r], sh);
            #pragma unroll
            for (int r = 0; r < 4; ++r) l_run[qi][r] += rs[r];
        }
        #pragma unroll
        for (int qi = 0; qi < 2; ++qi)
            #pragma unroll
            for (int ki = 0; ki < 2; ++ki)
                #pragma unroll
                for (int r = 0; r < 4; ++r)
                    p_lds[qi * 16 + l4 * 4 + r][ki * 16 + l15] = __float2bfloat16(p[qi][ki][r]);
        #pragma unroll
        for (int it = 0; it < 8; ++it)
            *(bf16x4*)&v_lds[it * 4 + l4][l15 * 4] = vreg[it];
        __syncthreads();
        bf16x8 pa[2];
        #pragma unroll
        for (int qi = 0; qi < 2; ++qi)
            pa[qi] = *(const bf16x8*)&p_lds[qi * 16 + l15][l4 * 8];
        bf16x8 vb[4];
        #pragma unroll
        for (int dt = 0; dt < 4; ++dt) {
            bf16x8 v;
            #pragma unroll
            for (int j = 0; j < 8; ++j)
                v[j] = *(const short*)&v_lds[l4 * 8 + j][dt * 16 + l15];
            vb[dt] = v;
        }
        #pragma unroll
        for (int qi = 0; qi < 2; ++qi)
            #pragma unroll
            for (int dt = 0; dt < 4; ++dt)
                oa[qi][dt] = __builtin_amdgcn_mfma_f32_16x16x32_bf16(pa[qi], vb[dt], oa[qi][dt], 0, 0, 0);
        __syncthreads();
    }
    #pragma unroll
    for (int qi = 0; qi < 2; ++qi)
        #pragma unroll
        for (int r = 0; r < 4; ++r) {
            int q = qt * 32 + qi * 16 + l4 * 4 + r;
            if (q < SS) {
                float inv = 1.0f / l_run[qi][r];
                __hip_bfloat16* orow = o + (tb + q) * 768 + hc;
                #pragma unroll
                for (int dt = 0; dt < 4; ++dt)
                    orow[dt * 16 + l15] = __float2bfloat16(oa[qi][dt][r] * inv);
            }
        }
}

// ---------------- workspace layout (float offsets) ----------------
static const size_t OFF_POOLED = 0;           //  9216 f
static const size_t OFF_IDX    = 10240;       //  4608 int
static const size_t OFF_H      = 16384;       //  3,551,232 f
static const size_t OFF_YB     = 3567616;     //  3,551,232 bf16 (1,775,616 f)
static const size_t OFF_OB     = 5343232;     //  3,551,232 bf16
static const size_t OFF_QKVB   = 7118848;     // 10,653,696 bf16 (5,326,848 f)
static const size_t OFF_WBUF   = 12445696;    //  7,077,888 bf16 (3,538,944 f)
static const size_t OFF_PWB    = 15984640;    //    589,824 bf16 (294,912 f)
static const size_t OFF_YF     = 16279552;    //     12,288 f
static const size_t OFF_BIG    = 16291840;    //  7,102,464 f (col+temp / hidden)
static const size_t OFF_PART   = 23394304;    // 14,204,928 f (4 x M*N split-K partials)
// total 37,599,232 floats = 150.4 MB

extern "C" void kernel_launch(void* const* d_in, const int* in_sizes, int n_in,
                              void* d_out, int out_size, void* d_ws, size_t ws_size,
                              hipStream_t stream) {
    const float* x       = (const float*)d_in[0];
    const float* patch_w = (const float*)d_in[1];
    const float* patch_b = (const float*)d_in[2];
    const float* cls_tok = (const float*)d_in[3];
    const float* pos_emb = (const float*)d_in[4];
    const float* ln1_g   = (const float*)d_in[5];
    const float* ln1_b   = (const float*)d_in[6];
    const float* Wqkv    = (const float*)d_in[7];
    const float* bqkv    = (const float*)d_in[8];
    const float* Wo      = (const float*)d_in[9];
    const float* bo      = (const float*)d_in[10];
    const float* ln2_g   = (const float*)d_in[11];
    const float* ln2_b   = (const float*)d_in[12];
    const float* W1      = (const float*)d_in[13];
    const float* b1      = (const float*)d_in[14];
    const float* W2      = (const float*)d_in[15];
    const float* b2      = (const float*)d_in[16];
    const float* lnf_g   = (const float*)d_in[17];
    const float* lnf_b   = (const float*)d_in[18];
    const float* fc_w    = (const float*)d_in[19];
    const float* fc_b    = (const float*)d_in[20];
    float* out = (float*)d_out;
    float* ws  = (float*)d_ws;

    float*          pooled = ws + OFF_POOLED;
    int*            idxsel = (int*)(ws + OFF_IDX);
    float*          h      = ws + OFF_H;
    __hip_bfloat16* yb     = (__hip_bfloat16*)(ws + OFF_YB);
    __hip_bfloat16* ob     = (__hip_bfloat16*)(ws + OFF_OB);
    __hip_bfloat16* qkvb   = (__hip_bfloat16*)(ws + OFF_QKVB);
    __hip_bfloat16* wbuf   = (__hip_bfloat16*)(ws + OFF_WBUF);
    __hip_bfloat16* pwb    = (__hip_bfloat16*)(ws + OFF_PWB);
    float*          yf     = ws + OFF_YF;
    float*          big    = ws + OFF_BIG;
    float*          part   = ws + OFF_PART;
    __hip_bfloat16* col    = (__hip_bfloat16*)big;             // 3,538,944 bf16
    float*          temp   = big + 1769472;                    // 3,538,944 f
    __hip_bfloat16* hidden = (__hip_bfloat16*)big;             // 14,204,928 bf16

    __hip_bfloat16* wqkvT = wbuf;                              // [2304][768]
    __hip_bfloat16* woT   = wbuf + 1769472;                    // [768][768]
    __hip_bfloat16* w1T   = wbuf + 2359296;                    // [3072][768]
    __hip_bfloat16* w2T   = wbuf + 4718592;                    // [768][3072]

    const int M = BB * SS;            // 4624
    const int MG = 37;                // ceil(4624/128)
    const int MN = M * DD;            // 3,551,232

    // ---- sparse selection + patch embedding ----
    pool_kernel<<<BB * NPATCH, 256, 0, stream>>>(x, pooled);
    topk_kernel<<<BB, 576, 0, stream>>>(pooled, idxsel);
    convert_bf16<<<(589824 + 255) / 256, 256, 0, stream>>>(patch_w, pwb, 589824);
    im2col_kernel<<<BB * KSEL, 256, 0, stream>>>(x, idxsel, col);
    gemm_bf16<float, 0, 0, 1><<<dim3(3, 36), 512, 0, stream>>>(
        col, pwb, temp, patch_b, nullptr, nullptr, 4608, DD, DD);
    assemble_tokens<<<BB * SS, 256, 0, stream>>>(temp, cls_tok, pos_emb, idxsel, h);

    // ---- transformer layers ----
    for (int i = 0; i < NLAY; ++i) {
        convert_layer<<<6912, 256, 0, stream>>>(Wqkv + (size_t)i * DD * 3 * DD,
                                                Wo + (size_t)i * DD * DD,
                                                W1 + (size_t)i * DD * FFD,
                                                W2 + (size_t)i * FFD * DD,
                                                wqkvT, woT, w1T, w2T);

        ln_kernel<__hip_bfloat16><<<M, 256, 0, stream>>>(h, yb, ln1_g + i * DD, ln1_b + i * DD, DD);
        gemm_bf16<__hip_bfloat16, 0, 0, 1><<<dim3(9, MG), 512, 0, stream>>>(
            yb, wqkvT, qkvb, bqkv + (size_t)i * 3 * DD, nullptr, nullptr, M, 3 * DD, DD);
        attn_fused<<<dim3(10, BB * NHD), 64, 0, stream>>>(qkvb, ob);
        // Wo: split-K x2 -> partials, combine adds bias+residual into h
        gemm_bf16<float, 0, 0, 2><<<dim3(3, MG, 2), 512, 0, stream>>>(
            ob, woT, (float*)nullptr, nullptr, nullptr, part, M, DD, DD);
        combine_res<2><<<(MN / 4 + 255) / 256, 256, 0, stream>>>(part, bo + (size_t)i * DD, h, MN, DD);
        ln_kernel<__hip_bfloat16><<<M, 256, 0, stream>>>(h, yb, ln2_g + i * DD, ln2_b + i * DD, DD);
        gemm_bf16<__hip_bfloat16, 1, 0, 1><<<dim3(12, MG), 512, 0, stream>>>(
            yb, w1T, hidden, b1 + (size_t)i * FFD, nullptr, nullptr, M, FFD, DD);
        // W2: split-K x4
        gemm_bf16<float, 0, 0, 4><<<dim3(3, MG, 4), 512, 0, stream>>>(
            hidden, w2T, (float*)nullptr, nullptr, nullptr, part, M, DD, FFD);
        combine_res<4><<<(MN / 4 + 255) / 256, 256, 0, stream>>>(part, b2 + (size_t)i * DD, h, MN, DD);
    }

    // ---- final LN on cls token + classifier head ----
    ln_kernel<float><<<BB, 256, 0, stream>>>(h, yf, lnf_g, lnf_b, (size_t)SS * DD);
    head_gemm<<<dim3(4, 4), 256, 0, stream>>>(yf, fc_w, fc_b, out);
}